// Round 1
// baseline (521.274 us; speedup 1.0000x reference)
//
#include <hip/hip_runtime.h>
#include <math.h>

// HeadAttention: B=4, S=4096, D=1024, DK=DV=64, fp32, causal.
// Round 1: all-fp32 vector implementation (no MFMA) — softmax logits have
// std ~1024 so low-precision QK^T flips argmax; fp32 is the safe baseline.
// ws layout: q [4*4096*64] | k [4*4096*64] | v [4*4096*64] floats (12 MB).

#define SEQ 4096
#define DIM 1024
#define HD  64
#define BQ  32
#define BKV 64

typedef __attribute__((ext_vector_type(4))) float f32x4;
typedef __attribute__((ext_vector_type(2))) float f32x2;

// ---------------- projection GEMM: Y[M,64] = X[M,1024] @ W[1024,64] --------
__global__ __launch_bounds__(256) void proj_kernel(
    const float* __restrict__ Xq, const float* __restrict__ Xk, const float* __restrict__ Xv,
    const float* __restrict__ Wq, const float* __restrict__ Wk, const float* __restrict__ Wv,
    float* __restrict__ Yq, float* __restrict__ Yk, float* __restrict__ Yv)
{
  const int which = blockIdx.y;
  const float* __restrict__ X = (which == 0) ? Xq : (which == 1) ? Xk : Xv;
  const float* __restrict__ W = (which == 0) ? Wq : (which == 1) ? Wk : Wv;
  float* __restrict__ Y       = (which == 0) ? Yq : (which == 1) ? Yk : Yv;

  __shared__ float As[32][68];  // [kk][row] (transposed) pad->stride 68
  __shared__ float Bs[32][68];  // [kk][col]

  const int t  = threadIdx.x;
  const int bm = blockIdx.x * 64;
  const int r0 = (t >> 4) * 4;   // 16x16 thread grid, 4x4 micro-tile
  const int c0 = (t & 15) * 4;

  const int arow = bm + (t >> 2);   // A: 64 rows x 32 k, 2 float4/thread
  const int ac0  = (t & 3) * 8;
  const int wrow = t >> 3;          // W: 32 k x 64 cols, 2 float4/thread
  const int wc0  = (t & 7) * 8;

  float acc[4][4] = {};

  for (int kt = 0; kt < DIM / 32; ++kt) {
    const float* ap = &X[(size_t)arow * DIM + kt * 32 + ac0];
    f32x4 a0 = *(const f32x4*)(ap);
    f32x4 a1 = *(const f32x4*)(ap + 4);
    const float* wp = &W[(size_t)(kt * 32 + wrow) * HD + wc0];
    f32x4 w0 = *(const f32x4*)(wp);
    f32x4 w1 = *(const f32x4*)(wp + 4);
    __syncthreads();  // previous tile's compute done before overwrite
#pragma unroll
    for (int u = 0; u < 4; ++u) As[ac0 + u][t >> 2] = a0[u];
#pragma unroll
    for (int u = 0; u < 4; ++u) As[ac0 + 4 + u][t >> 2] = a1[u];
    *(f32x4*)&Bs[wrow][wc0]     = w0;
    *(f32x4*)&Bs[wrow][wc0 + 4] = w1;
    __syncthreads();
#pragma unroll
    for (int kk = 0; kk < 32; ++kk) {
      f32x4 a = *(const f32x4*)&As[kk][r0];
      f32x4 w = *(const f32x4*)&Bs[kk][c0];
#pragma unroll
      for (int i = 0; i < 4; ++i)
#pragma unroll
        for (int j = 0; j < 4; ++j)
          acc[i][j] = fmaf(a[i], w[j], acc[i][j]);
    }
  }
#pragma unroll
  for (int i = 0; i < 4; ++i) {
    f32x4 o = { acc[i][0], acc[i][1], acc[i][2], acc[i][3] };
    *(f32x4*)&Y[(size_t)(bm + r0 + i) * HD + c0] = o;
  }
}

// ---------------- flash attention, fp32, causal ----------------------------
// Block: 256 threads; q-tile BQ=32 rows; kv-tile BKV=64.
// Thread (r0=(t>>5)*4 rows, c0=(t&31)*2 cols). Row owners = 32 contiguous
// lanes -> shfl_xor reductions. Block x handles q-tiles x and 127-x so all
// 256 blocks do ~65 kv-tiles (causal load balance at 1 block/CU).
__global__ __launch_bounds__(256) void attn_kernel(
    const float* __restrict__ qm, const float* __restrict__ km,
    const float* __restrict__ vm, float* __restrict__ om)
{
  __shared__ float Qt[64][36];  // [d][qrow], pre-scaled by 1/8
  __shared__ float Kt[64][68];  // [d][kvrow]
  __shared__ float Vs[64][68];  // [kvrow][vcol]
  __shared__ float Pt[64][36];  // [kvrow][qrow]

  const int t = threadIdx.x;
  const int b = blockIdx.y;
  const int x = blockIdx.x;

  const int r0 = (t >> 5) * 4;
  const int c0 = (t & 31) * 2;

  const float* qb = qm + (size_t)b * SEQ * HD;
  const float* kb = km + (size_t)b * SEQ * HD;
  const float* vb = vm + (size_t)b * SEQ * HD;
  float*       ob = om + (size_t)b * SEQ * HD;

  for (int sel = 0; sel < 2; ++sel) {
    const int qi    = sel ? (127 - x) : x;
    const int qbase = qi * BQ;

    __syncthreads();  // previous q-tile's Qt reads done
    {
      const int qr = t >> 3;          // 32 rows x 64 d, 2 float4/thread
      const int qc = (t & 7) * 8;
      const float* qp = &qb[(size_t)(qbase + qr) * HD + qc];
      f32x4 q0 = *(const f32x4*)(qp);
      f32x4 q1 = *(const f32x4*)(qp + 4);
#pragma unroll
      for (int u = 0; u < 4; ++u) Qt[qc + u][qr]     = q0[u] * 0.125f;
#pragma unroll
      for (int u = 0; u < 4; ++u) Qt[qc + 4 + u][qr] = q1[u] * 0.125f;
    }

    float m[4], l[4], o[4][2];
#pragma unroll
    for (int i = 0; i < 4; ++i) {
      m[i] = -INFINITY; l[i] = 0.f; o[i][0] = 0.f; o[i][1] = 0.f;
    }

    const int ntiles = (qi >> 1) + 1;
    for (int kt = 0; kt < ntiles; ++kt) {
      const int j0 = kt * BKV;
      const int kr = t >> 2;          // 64 rows x 64 d, 4 float4/thread
      const int kc = (t & 3) * 16;
      f32x4 krg[4], vrg[4];
      const float* kp = &kb[(size_t)(j0 + kr) * HD + kc];
      const float* vp = &vb[(size_t)(j0 + kr) * HD + kc];
#pragma unroll
      for (int u = 0; u < 4; ++u) krg[u] = *(const f32x4*)(kp + 4 * u);
#pragma unroll
      for (int u = 0; u < 4; ++u) vrg[u] = *(const f32x4*)(vp + 4 * u);
      __syncthreads();  // previous tile's Kt/Vs/Pt reads done
#pragma unroll
      for (int u = 0; u < 4; ++u)
#pragma unroll
        for (int w = 0; w < 4; ++w) Kt[kc + 4 * u + w][kr] = krg[u][w];
#pragma unroll
      for (int u = 0; u < 4; ++u) *(f32x4*)&Vs[kr][kc + 4 * u] = vrg[u];
      __syncthreads();

      // ---- scores: s[i][j] = (q_row . k_row) * 1/8 (scale folded into Qt)
      float s[4][2] = {};
#pragma unroll 16
      for (int d = 0; d < 64; ++d) {
        f32x4 qv = *(const f32x4*)&Qt[d][r0];
        f32x2 kv = *(const f32x2*)&Kt[d][c0];
#pragma unroll
        for (int i = 0; i < 4; ++i) {
          s[i][0] = fmaf(qv[i], kv[0], s[i][0]);
          s[i][1] = fmaf(qv[i], kv[1], s[i][1]);
        }
      }

      // ---- causal mask (diagonal tile is always the last tile)
      if (kt == ntiles - 1) {
#pragma unroll
        for (int i = 0; i < 4; ++i)
#pragma unroll
          for (int j = 0; j < 2; ++j)
            if (j0 + c0 + j > qbase + r0 + i) s[i][j] = -INFINITY;
      }

      // ---- online softmax update (per row: reduce across 32 lanes)
#pragma unroll
      for (int i = 0; i < 4; ++i) {
        float mx = fmaxf(s[i][0], s[i][1]);
#pragma unroll
        for (int off = 16; off > 0; off >>= 1)
          mx = fmaxf(mx, __shfl_xor(mx, off));
        const float mn = fmaxf(m[i], mx);
        const float p0 = __expf(s[i][0] - mn);
        const float p1 = __expf(s[i][1] - mn);
        float ps = p0 + p1;
#pragma unroll
        for (int off = 16; off > 0; off >>= 1)
          ps += __shfl_xor(ps, off);
        const float alpha = __expf(m[i] - mn);
        l[i] = l[i] * alpha + ps;
        m[i] = mn;
        o[i][0] *= alpha;
        o[i][1] *= alpha;
        Pt[c0][r0 + i]     = p0;
        Pt[c0 + 1][r0 + i] = p1;
      }
      __syncthreads();  // Pt visible before PV

      // ---- PV accumulate
#pragma unroll 16
      for (int j = 0; j < BKV; ++j) {
        f32x4 pv = *(const f32x4*)&Pt[j][r0];
        f32x2 vv = *(const f32x2*)&Vs[j][c0];
#pragma unroll
        for (int i = 0; i < 4; ++i) {
          o[i][0] = fmaf(pv[i], vv[0], o[i][0]);
          o[i][1] = fmaf(pv[i], vv[1], o[i][1]);
        }
      }
    }

    // ---- epilogue
#pragma unroll
    for (int i = 0; i < 4; ++i) {
      const float inv = 1.0f / l[i];
      f32x2 ov = { o[i][0] * inv, o[i][1] * inv };
      *(f32x2*)&ob[(size_t)(qbase + r0 + i) * HD + c0] = ov;
    }
  }
}

extern "C" void kernel_launch(void* const* d_in, const int* in_sizes, int n_in,
                              void* d_out, int out_size, void* d_ws, size_t ws_size,
                              hipStream_t stream) {
  const float* query = (const float*)d_in[0];
  const float* key   = (const float*)d_in[1];
  const float* value = (const float*)d_in[2];
  const float* Wq    = (const float*)d_in[3];
  const float* Wk    = (const float*)d_in[4];
  const float* Wv    = (const float*)d_in[5];
  // d_in[6] is the causal tril mask — implemented analytically, not read.

  float* out = (float*)d_out;
  float* ws  = (float*)d_ws;
  float* qp  = ws;                              // 4*4096*64 floats
  float* kp  = ws + (size_t)4 * SEQ * HD;       // 4*4096*64 floats
  float* vp  = ws + (size_t)8 * SEQ * HD;       // 4*4096*64 floats

  dim3 pgrid(16384 / 64, 3);
  proj_kernel<<<pgrid, 256, 0, stream>>>(query, key, value, Wq, Wk, Wv, qp, kp, vp);

  dim3 agrid(64, 4);
  attn_kernel<<<agrid, 256, 0, stream>>>(qp, kp, vp, out);
}

// Round 2
// 165.722 us; speedup vs baseline: 3.1455x; 3.1455x over previous
//
#include <hip/hip_runtime.h>
#include <math.h>

// HeadAttention B=4, S=4096, D=1024, DK=DV=64, fp32 in/out, causal.
// Round 2: fp16x3 MFMA everywhere. Logit std ~1024 => plain f16 flips
// softmax argmax; hi/lo f16 split (3 MFMAs) gives ~2^-22 rel => safe.
// Softmax runs in exp2 domain (log2e/8 folded into Wq at pre-split).
// Attention: split-4 over kv-tile parity + (qb,63-qb) pairing => 512
// equal-work blocks (2/CU), partials merged by combine kernel.

#define SEQ 4096
#define DIM 1024
#define HD  64
#define NB  4
#define NSPLIT 4

typedef __attribute__((ext_vector_type(4))) float    f32x4;
typedef __attribute__((ext_vector_type(8))) _Float16 f16x8;
typedef __attribute__((ext_vector_type(4))) _Float16 f16x4;

#define MFMA16 __builtin_amdgcn_mfma_f32_16x16x32_f16

// swizzled offset into a [row][64] f16 LDS tile: XOR 16B-chunk id with row&7
// (lanes 0..15 read consecutive rows at same k-range -> conflict-free)
__device__ __forceinline__ int SW(int row, int k) {
  return row * 64 + (k ^ ((row & 7) << 3));
}

// ---------- W pre-split: wt_h/wt_l[mat][col][k] f16, Wq scaled by log2e/8 --
__global__ __launch_bounds__(256) void wsplit_kernel(
    const float* __restrict__ Wq, const float* __restrict__ Wk,
    const float* __restrict__ Wv, _Float16* __restrict__ wth,
    _Float16* __restrict__ wtl)
{
  const int mat = blockIdx.x;   // 0..2
  const int col = blockIdx.y;   // 0..63
  const float* __restrict__ W = (mat == 0) ? Wq : (mat == 1) ? Wk : Wv;
  const float scale = (mat == 0) ? 0.18033688011112042f : 1.0f;  // log2(e)/8
  const size_t base = ((size_t)mat * HD + col) * DIM;
#pragma unroll
  for (int u = 0; u < 4; ++u) {
    const int k = threadIdx.x + u * 256;
    const float y = W[(size_t)k * HD + col] * scale;
    const _Float16 h = (_Float16)y;
    wth[base + k] = h;
    wtl[base + k] = (_Float16)(y - (float)h);
  }
}

// ---------- projection: fp16x3 MFMA, barrier-free --------------------------
// grid (256, 3), 256 threads (4 waves x 16 rows). Y = X[16384,1024]@W[1024,64]
__global__ __launch_bounds__(256) void proj_kernel(
    const float* __restrict__ Xq, const float* __restrict__ Xk,
    const float* __restrict__ Xv,
    const _Float16* __restrict__ wth, const _Float16* __restrict__ wtl,
    _Float16* __restrict__ qh, _Float16* __restrict__ ql,
    _Float16* __restrict__ kh, _Float16* __restrict__ kl,
    _Float16* __restrict__ vt)
{
  const int which = blockIdx.y;
  const float* __restrict__ X = (which == 0) ? Xq : (which == 1) ? Xk : Xv;

  const int t = threadIdx.x, lane = t & 63, w = t >> 6;
  const size_t mrow = (size_t)blockIdx.x * 64 + w * 16 + (lane & 15);
  const float* xp = X + mrow * DIM + ((lane >> 4) * 8);
  const _Float16* wbh = wth + ((size_t)which * HD + (lane & 15)) * DIM + ((lane >> 4) * 8);
  const _Float16* wbl = wtl + ((size_t)which * HD + (lane & 15)) * DIM + ((lane >> 4) * 8);

  f32x4 acc[4] = {{0,0,0,0},{0,0,0,0},{0,0,0,0},{0,0,0,0}};

  for (int kb = 0; kb < DIM; kb += 32) {
    f32x4 x0 = *(const f32x4*)(xp + kb);
    f32x4 x1 = *(const f32x4*)(xp + kb + 4);
    f16x8 xh, xl;
#pragma unroll
    for (int j = 0; j < 4; ++j) {
      _Float16 h = (_Float16)x0[j];
      xh[j] = h; xl[j] = (_Float16)(x0[j] - (float)h);
    }
#pragma unroll
    for (int j = 0; j < 4; ++j) {
      _Float16 h = (_Float16)x1[j];
      xh[j + 4] = h; xl[j + 4] = (_Float16)(x1[j] - (float)h);
    }
#pragma unroll
    for (int ct = 0; ct < 4; ++ct) {
      f16x8 bh = *(const f16x8*)(wbh + (size_t)ct * 16 * DIM + kb);
      f16x8 bl = *(const f16x8*)(wbl + (size_t)ct * 16 * DIM + kb);
      acc[ct] = MFMA16(xh, bh, acc[ct], 0, 0, 0);
      acc[ct] = MFMA16(xl, bh, acc[ct], 0, 0, 0);
      acc[ct] = MFMA16(xh, bl, acc[ct], 0, 0, 0);
    }
  }

  // epilogue: C layout col=lane&15, row=(lane>>4)*4+r
  const size_t orow0 = (size_t)blockIdx.x * 64 + w * 16 + (lane >> 4) * 4;
  if (which < 2) {
    _Float16* oh = (which == 0) ? qh : kh;
    _Float16* ol = (which == 0) ? ql : kl;
#pragma unroll
    for (int ct = 0; ct < 4; ++ct)
#pragma unroll
      for (int r = 0; r < 4; ++r) {
        const float y = acc[ct][r];
        const _Float16 h = (_Float16)y;
        const size_t idx = (orow0 + r) * HD + ct * 16 + (lane & 15);
        oh[idx] = h;
        ol[idx] = (_Float16)(y - (float)h);
      }
  } else {
    const int batch = (int)(orow0 >> 12);
    const int pos = (int)(orow0 & 4095);
#pragma unroll
    for (int ct = 0; ct < 4; ++ct) {
      f16x4 hv;
#pragma unroll
      for (int r = 0; r < 4; ++r) hv[r] = (_Float16)acc[ct][r];
      *(f16x4*)&vt[((size_t)batch * HD + ct * 16 + (lane & 15)) * SEQ + pos] = hv;
    }
  }
}

// ---------- flash attention, fp16x3 QK + f16 PV, split-4 partials ----------
// grid (128, 4): x -> pair p=x>>2 (q-blocks p and 63-p), parity s=x&3.
__global__ __launch_bounds__(256) void attn_kernel(
    const _Float16* __restrict__ qh, const _Float16* __restrict__ ql,
    const _Float16* __restrict__ kh, const _Float16* __restrict__ kl,
    const _Float16* __restrict__ vt,
    _Float16* __restrict__ opart, float* __restrict__ mlp)
{
  __shared__ __attribute__((aligned(16))) _Float16 Ksh[64 * 64];
  __shared__ __attribute__((aligned(16))) _Float16 Ksl[64 * 64];
  __shared__ __attribute__((aligned(16))) _Float16 Vs [64 * 64];
  __shared__ __attribute__((aligned(16))) _Float16 Pt [64 * 64];

  const int t = threadIdx.x, lane = t & 63, w = t >> 6;
  const int b = blockIdx.y;
  const int p = blockIdx.x >> 2, s = blockIdx.x & 3;
  const size_t bS = (size_t)b * SEQ;

  for (int sel = 0; sel < 2; ++sel) {
    const int qb = sel ? (63 - p) : p;
    const int qrow0 = qb * 64 + w * 16;
    const int nt = (qb >= s) ? ((qb - s) >> 2) + 1 : 0;  // kv tiles ≡ s mod 4

    float m[4] = {-INFINITY, -INFINITY, -INFINITY, -INFINITY};
    float lsum[4] = {0.f, 0.f, 0.f, 0.f};
    f32x4 o[4] = {{0,0,0,0},{0,0,0,0},{0,0,0,0},{0,0,0,0}};

    if (nt > 0) {
      const _Float16* qhp = qh + (bS + qrow0 + (lane & 15)) * HD + ((lane >> 4) * 8);
      const _Float16* qlp = ql + (bS + qrow0 + (lane & 15)) * HD + ((lane >> 4) * 8);
      f16x8 qhf[2], qlf[2];
      qhf[0] = *(const f16x8*)(qhp);      qhf[1] = *(const f16x8*)(qhp + 32);
      qlf[0] = *(const f16x8*)(qlp);      qlf[1] = *(const f16x8*)(qlp + 32);

      for (int i = 0; i < nt; ++i) {
        const int kt = s + 4 * i;
        const int j0 = kt * 64;

        __syncthreads();  // previous tile's LDS reads complete
#pragma unroll
        for (int c = 0; c < 2; ++c) {
          const int lin = t + 256 * c;
          const int row = lin >> 3, d8 = (lin & 7) * 8;
          const int dst = SW(row, d8);
          *(f16x8*)&Ksh[dst] = *(const f16x8*)&kh[(bS + j0 + row) * HD + d8];
          *(f16x8*)&Ksl[dst] = *(const f16x8*)&kl[(bS + j0 + row) * HD + d8];
          *(f16x8*)&Vs[dst]  = *(const f16x8*)&vt[((size_t)b * HD + row) * SEQ + j0 + d8];
        }
        __syncthreads();

        // ---- QK^T: fp16x3
        f32x4 sacc[4] = {{0,0,0,0},{0,0,0,0},{0,0,0,0},{0,0,0,0}};
#pragma unroll
        for (int ks = 0; ks < 2; ++ks)
#pragma unroll
          for (int kt4 = 0; kt4 < 4; ++kt4) {
            const int ba = SW(kt4 * 16 + (lane & 15), ks * 32 + (lane >> 4) * 8);
            f16x8 bh = *(const f16x8*)&Ksh[ba];
            f16x8 bl = *(const f16x8*)&Ksl[ba];
            sacc[kt4] = MFMA16(qhf[ks], bh, sacc[kt4], 0, 0, 0);
            sacc[kt4] = MFMA16(qlf[ks], bh, sacc[kt4], 0, 0, 0);
            sacc[kt4] = MFMA16(qhf[ks], bl, sacc[kt4], 0, 0, 0);
          }

        // ---- causal mask on the diagonal tile
        if (kt == qb) {
#pragma unroll
          for (int kt4 = 0; kt4 < 4; ++kt4) {
            const int key = j0 + kt4 * 16 + (lane & 15);
#pragma unroll
            for (int r = 0; r < 4; ++r)
              if (key > qrow0 + (lane >> 4) * 4 + r) sacc[kt4][r] = -INFINITY;
          }
        }

        // ---- online softmax (exp2 domain), P -> LDS f16
        float alf[4];
#pragma unroll
        for (int r = 0; r < 4; ++r) {
          float mx = fmaxf(fmaxf(sacc[0][r], sacc[1][r]),
                           fmaxf(sacc[2][r], sacc[3][r]));
          mx = fmaxf(mx, __shfl_xor(mx, 1));
          mx = fmaxf(mx, __shfl_xor(mx, 2));
          mx = fmaxf(mx, __shfl_xor(mx, 4));
          mx = fmaxf(mx, __shfl_xor(mx, 8));
          const float mn = fmaxf(m[r], mx);
          const float al = exp2f(m[r] - mn);
          const int prow = w * 16 + (lane >> 4) * 4 + r;
          float ps = 0.f;
#pragma unroll
          for (int kt4 = 0; kt4 < 4; ++kt4) {
            const _Float16 ph = (_Float16)exp2f(sacc[kt4][r] - mn);
            ps += (float)ph;
            Pt[SW(prow, kt4 * 16 + (lane & 15))] = ph;
          }
          ps += __shfl_xor(ps, 1);
          ps += __shfl_xor(ps, 2);
          ps += __shfl_xor(ps, 4);
          ps += __shfl_xor(ps, 8);
          lsum[r] = lsum[r] * al + ps;
          m[r] = mn;
          alf[r] = al;
        }
        const f32x4 av = {alf[0], alf[1], alf[2], alf[3]};
#pragma unroll
        for (int ct = 0; ct < 4; ++ct) o[ct] *= av;

        // ---- PV (per-wave Pt region; lgkmcnt ordering handled by compiler)
#pragma unroll
        for (int ks = 0; ks < 2; ++ks) {
          f16x8 pa = *(const f16x8*)&Pt[SW(w * 16 + (lane & 15),
                                           ks * 32 + (lane >> 4) * 8)];
#pragma unroll
          for (int ct = 0; ct < 4; ++ct) {
            f16x8 vb = *(const f16x8*)&Vs[SW(ct * 16 + (lane & 15),
                                             ks * 32 + (lane >> 4) * 8)];
            o[ct] = MFMA16(pa, vb, o[ct], 0, 0, 0);
          }
        }
      }
    }

    // ---- write partials: normalized o (f16) + (m, l) f32
    f32x4 invv;
#pragma unroll
    for (int r = 0; r < 4; ++r) invv[r] = (nt > 0) ? 1.0f / lsum[r] : 0.0f;
    const size_t ridx0 = (size_t)(b * NSPLIT + s) * SEQ + qrow0 + (lane >> 4) * 4;
#pragma unroll
    for (int ct = 0; ct < 4; ++ct)
#pragma unroll
      for (int r = 0; r < 4; ++r)
        opart[(ridx0 + r) * HD + ct * 16 + (lane & 15)] =
            (_Float16)(o[ct][r] * invv[r]);
    if ((lane & 15) == 0) {
#pragma unroll
      for (int r = 0; r < 4; ++r) {
        mlp[(ridx0 + r) * 2]     = m[r];
        mlp[(ridx0 + r) * 2 + 1] = lsum[r];
      }
    }
  }
}

// ---------- combine the 4 kv-parity partials -------------------------------
__global__ __launch_bounds__(256) void combine_kernel(
    const _Float16* __restrict__ opart, const float* __restrict__ mlp,
    float* __restrict__ out)
{
  const int g = blockIdx.x * 256 + threadIdx.x;   // 262144
  const int row = g >> 4;
  const int cq = (g & 15) * 4;
  const int b = row >> 12, pos = row & 4095;

  float mv[4], lv[4], msx = -INFINITY;
#pragma unroll
  for (int s = 0; s < 4; ++s) {
    const size_t ri = (size_t)(b * NSPLIT + s) * SEQ + pos;
    mv[s] = mlp[ri * 2];
    lv[s] = mlp[ri * 2 + 1];
    msx = fmaxf(msx, mv[s]);
  }
  f32x4 num = {0.f, 0.f, 0.f, 0.f};
  float L = 0.f;
#pragma unroll
  for (int s = 0; s < 4; ++s) {
    const float wgt = lv[s] * exp2f(mv[s] - msx);
    L += wgt;
    const size_t ri = (size_t)(b * NSPLIT + s) * SEQ + pos;
    const f16x4 ov = *(const f16x4*)&opart[ri * HD + cq];
#pragma unroll
    for (int j = 0; j < 4; ++j) num[j] += wgt * (float)ov[j];
  }
  const float inv = 1.0f / L;
  f32x4 res = {num[0] * inv, num[1] * inv, num[2] * inv, num[3] * inv};
  *(f32x4*)&out[(size_t)row * HD + cq] = res;
}

extern "C" void kernel_launch(void* const* d_in, const int* in_sizes, int n_in,
                              void* d_out, int out_size, void* d_ws, size_t ws_size,
                              hipStream_t stream) {
  const float* query = (const float*)d_in[0];
  const float* key   = (const float*)d_in[1];
  const float* value = (const float*)d_in[2];
  const float* Wq    = (const float*)d_in[3];
  const float* Wk    = (const float*)d_in[4];
  const float* Wv    = (const float*)d_in[5];
  // d_in[6]: causal mask, handled analytically.

  float* out = (float*)d_out;

  // ws layout (bytes): f16 region then f32 region
  _Float16* qh  = (_Float16*)d_ws;                       // 1,048,576 elems
  _Float16* ql  = qh  + (size_t)NB * SEQ * HD;
  _Float16* kh  = ql  + (size_t)NB * SEQ * HD;
  _Float16* kl  = kh  + (size_t)NB * SEQ * HD;
  _Float16* vt  = kl  + (size_t)NB * SEQ * HD;           // [b][64][4096]
  _Float16* wth = vt  + (size_t)NB * SEQ * HD;           // [3][64][1024]
  _Float16* wtl = wth + (size_t)3 * HD * DIM;
  _Float16* opart = wtl + (size_t)3 * HD * DIM;          // [b*4+s][4096][64]
  float* mlp = (float*)(opart + (size_t)NB * NSPLIT * SEQ * HD);  // [..][4096][2]

  wsplit_kernel<<<dim3(3, 64), 256, 0, stream>>>(Wq, Wk, Wv, wth, wtl);
  proj_kernel<<<dim3(256, 3), 256, 0, stream>>>(query, key, value, wth, wtl,
                                                qh, ql, kh, kl, vt);
  attn_kernel<<<dim3(128, NB), 256, 0, stream>>>(qh, ql, kh, kl, vt, opart, mlp);
  combine_kernel<<<1024, 256, 0, stream>>>(opart, mlp, out);
}

// Round 3
// 156.409 us; speedup vs baseline: 3.3328x; 1.0595x over previous
//
#include <hip/hip_runtime.h>
#include <math.h>

// HeadAttention B=4, S=4096, D=1024, DK=DV=64, fp32 in/out, causal.
// Round 3: proj rewritten as m97-style global_load_lds double-buffered GEMM
// (round-2 proj was latency-bound at VGPR=36 with direct strided loads).
// fp16x3 MFMA numerics unchanged. Attention kernel unchanged from round 2.

#define SEQ 4096
#define DIM 1024
#define HD  64
#define NB  4
#define NSPLIT 4

typedef __attribute__((ext_vector_type(4))) float    f32x4;
typedef __attribute__((ext_vector_type(8))) _Float16 f16x8;
typedef __attribute__((ext_vector_type(4))) _Float16 f16x4;

#define MFMA16 __builtin_amdgcn_mfma_f32_16x16x32_f16

// async 16B global->LDS (linear dest: wave-uniform base + lane*16)
#define GLOAD_LDS16(g, l)                                          \
  __builtin_amdgcn_global_load_lds(                                \
      (const __attribute__((address_space(1))) void*)(g),          \
      (__attribute__((address_space(3))) void*)(l), 16, 0, 0)

// swizzled offset into a [row][64] f16 LDS tile (attn): XOR 16B-chunk with row&7
__device__ __forceinline__ int SW(int row, int k) {
  return row * 64 + (k ^ ((row & 7) << 3));
}

// ---------- W pre-split: wt_h/wt_l[mat][col][k] f16, Wq scaled by log2e/8 --
__global__ __launch_bounds__(256) void wsplit_kernel(
    const float* __restrict__ Wq, const float* __restrict__ Wk,
    const float* __restrict__ Wv, _Float16* __restrict__ wth,
    _Float16* __restrict__ wtl)
{
  const int mat = blockIdx.x;   // 0..2
  const int col = blockIdx.y;   // 0..63
  const float* __restrict__ W = (mat == 0) ? Wq : (mat == 1) ? Wk : Wv;
  const float scale = (mat == 0) ? 0.18033688011112042f : 1.0f;  // log2(e)/8
  const size_t base = ((size_t)mat * HD + col) * DIM;
#pragma unroll
  for (int u = 0; u < 4; ++u) {
    const int k = threadIdx.x + u * 256;
    const float y = W[(size_t)k * HD + col] * scale;
    const _Float16 h = (_Float16)y;
    wth[base + k] = h;
    wtl[base + k] = (_Float16)(y - (float)h);
  }
}

// ---------- projection: LDS-staged fp16x3 MFMA -----------------------------
// grid (256, 3), 256 threads (4 waves x 16 rows). Y = X[16384,1024]@W[1024,64]
// X staged in 64x64 f32 K-tiles, double-buffered, global_load_lds width 16.
// LDS 16B-chunk (row, cc) holds X chunk (cc ^ (row&15)): source pre-swizzled,
// read side applies the same XOR -> conflict-free ds_read_b128.
__global__ __launch_bounds__(256) void proj_kernel(
    const float* __restrict__ Xq, const float* __restrict__ Xk,
    const float* __restrict__ Xv,
    const _Float16* __restrict__ wth, const _Float16* __restrict__ wtl,
    _Float16* __restrict__ qh, _Float16* __restrict__ ql,
    _Float16* __restrict__ kh, _Float16* __restrict__ kl,
    _Float16* __restrict__ vt)
{
  __shared__ __attribute__((aligned(16))) float Xs[2][64 * 64];

  const int which = blockIdx.y;
  const float* __restrict__ X = (which == 0) ? Xq : (which == 1) ? Xk : Xv;

  const int t = threadIdx.x, lane = t & 63, w = t >> 6;
  const int bm = blockIdx.x * 64;

  // staging: thread handles chunks c = (w*4+i)*64 + lane (16B units);
  // row = c>>4, cc = lane&15, source chunk = cc ^ (row&15).
  const float* gsrc[4];
  int lofs[4];  // float offset of the wave-uniform 1KB slab within a buffer
#pragma unroll
  for (int i = 0; i < 4; ++i) {
    const int row = w * 16 + i * 4 + (lane >> 4);
    const int srcc = (lane & 15) ^ (row & 15);
    gsrc[i] = X + (size_t)(bm + row) * DIM + srcc * 4;
    lofs[i] = (w * 4 + i) * 256;
  }

  // W fragment base (B-operand: col = lane&15, k = (lane>>4)*8)
  const size_t wb = ((size_t)which * HD + (lane & 15)) * DIM + ((lane >> 4) * 8);
  const _Float16* wbh = wth + wb;
  const _Float16* wbl = wtl + wb;

  const int frow = lane & 15;
  const int ldsrow = w * 16 + frow;

  f32x4 acc[4] = {{0,0,0,0},{0,0,0,0},{0,0,0,0},{0,0,0,0}};

  // prologue: stage tile 0 into buf 0
#pragma unroll
  for (int i = 0; i < 4; ++i) GLOAD_LDS16(gsrc[i], &Xs[0][lofs[i]]);

  for (int kt = 0; kt < DIM / 64; ++kt) {
    __syncthreads();  // current tile staged; prior compute done
    const int cur = kt & 1;
    if (kt + 1 < DIM / 64) {
      const int nxt = cur ^ 1;
#pragma unroll
      for (int i = 0; i < 4; ++i)
        GLOAD_LDS16(gsrc[i] + (kt + 1) * 64, &Xs[nxt][lofs[i]]);
    }
    const float* xt = &Xs[cur][0];
#pragma unroll
    for (int ks = 0; ks < 2; ++ks) {
      const int cc0 = ks * 8 + (lane >> 4) * 2;
      f32x4 x0 = *(const f32x4*)&xt[ldsrow * 64 + ((cc0 ^ frow) * 4)];
      f32x4 x1 = *(const f32x4*)&xt[ldsrow * 64 + (((cc0 + 1) ^ frow) * 4)];
      f16x8 xh, xl;
#pragma unroll
      for (int j = 0; j < 4; ++j) {
        const _Float16 h = (_Float16)x0[j];
        xh[j] = h; xl[j] = (_Float16)(x0[j] - (float)h);
      }
#pragma unroll
      for (int j = 0; j < 4; ++j) {
        const _Float16 h = (_Float16)x1[j];
        xh[j + 4] = h; xl[j + 4] = (_Float16)(x1[j] - (float)h);
      }
      const size_t ko = (size_t)kt * 64 + ks * 32;
#pragma unroll
      for (int ct = 0; ct < 4; ++ct) {
        f16x8 bh = *(const f16x8*)(wbh + (size_t)ct * 16 * DIM + ko);
        f16x8 bl = *(const f16x8*)(wbl + (size_t)ct * 16 * DIM + ko);
        acc[ct] = MFMA16(xh, bh, acc[ct], 0, 0, 0);
        acc[ct] = MFMA16(xl, bh, acc[ct], 0, 0, 0);
        acc[ct] = MFMA16(xh, bl, acc[ct], 0, 0, 0);
      }
    }
  }

  // epilogue: C layout col=lane&15, row=(lane>>4)*4+r
  const size_t orow0 = (size_t)bm + w * 16 + (lane >> 4) * 4;
  if (which < 2) {
    _Float16* oh = (which == 0) ? qh : kh;
    _Float16* ol = (which == 0) ? ql : kl;
#pragma unroll
    for (int ct = 0; ct < 4; ++ct)
#pragma unroll
      for (int r = 0; r < 4; ++r) {
        const float y = acc[ct][r];
        const _Float16 h = (_Float16)y;
        const size_t idx = (orow0 + r) * HD + ct * 16 + (lane & 15);
        oh[idx] = h;
        ol[idx] = (_Float16)(y - (float)h);
      }
  } else {
    const int batch = (int)(orow0 >> 12);
    const int pos = (int)(orow0 & 4095);
#pragma unroll
    for (int ct = 0; ct < 4; ++ct) {
      f16x4 hv;
#pragma unroll
      for (int r = 0; r < 4; ++r) hv[r] = (_Float16)acc[ct][r];
      *(f16x4*)&vt[((size_t)batch * HD + ct * 16 + (lane & 15)) * SEQ + pos] = hv;
    }
  }
}

// ---------- flash attention, fp16x3 QK + f16 PV, split-4 partials ----------
// grid (128, 4): x -> pair p=x>>2 (q-blocks p and 63-p), parity s=x&3.
__global__ __launch_bounds__(256) void attn_kernel(
    const _Float16* __restrict__ qh, const _Float16* __restrict__ ql,
    const _Float16* __restrict__ kh, const _Float16* __restrict__ kl,
    const _Float16* __restrict__ vt,
    _Float16* __restrict__ opart, float* __restrict__ mlp)
{
  __shared__ __attribute__((aligned(16))) _Float16 Ksh[64 * 64];
  __shared__ __attribute__((aligned(16))) _Float16 Ksl[64 * 64];
  __shared__ __attribute__((aligned(16))) _Float16 Vs [64 * 64];
  __shared__ __attribute__((aligned(16))) _Float16 Pt [64 * 64];

  const int t = threadIdx.x, lane = t & 63, w = t >> 6;
  const int b = blockIdx.y;
  const int p = blockIdx.x >> 2, s = blockIdx.x & 3;
  const size_t bS = (size_t)b * SEQ;

  for (int sel = 0; sel < 2; ++sel) {
    const int qb = sel ? (63 - p) : p;
    const int qrow0 = qb * 64 + w * 16;
    const int nt = (qb >= s) ? ((qb - s) >> 2) + 1 : 0;  // kv tiles ≡ s mod 4

    float m[4] = {-INFINITY, -INFINITY, -INFINITY, -INFINITY};
    float lsum[4] = {0.f, 0.f, 0.f, 0.f};
    f32x4 o[4] = {{0,0,0,0},{0,0,0,0},{0,0,0,0},{0,0,0,0}};

    if (nt > 0) {
      const _Float16* qhp = qh + (bS + qrow0 + (lane & 15)) * HD + ((lane >> 4) * 8);
      const _Float16* qlp = ql + (bS + qrow0 + (lane & 15)) * HD + ((lane >> 4) * 8);
      f16x8 qhf[2], qlf[2];
      qhf[0] = *(const f16x8*)(qhp);      qhf[1] = *(const f16x8*)(qhp + 32);
      qlf[0] = *(const f16x8*)(qlp);      qlf[1] = *(const f16x8*)(qlp + 32);

      for (int i = 0; i < nt; ++i) {
        const int kt = s + 4 * i;
        const int j0 = kt * 64;

        __syncthreads();  // previous tile's LDS reads complete
#pragma unroll
        for (int c = 0; c < 2; ++c) {
          const int lin = t + 256 * c;
          const int row = lin >> 3, d8 = (lin & 7) * 8;
          const int dst = SW(row, d8);
          *(f16x8*)&Ksh[dst] = *(const f16x8*)&kh[(bS + j0 + row) * HD + d8];
          *(f16x8*)&Ksl[dst] = *(const f16x8*)&kl[(bS + j0 + row) * HD + d8];
          *(f16x8*)&Vs[dst]  = *(const f16x8*)&vt[((size_t)b * HD + row) * SEQ + j0 + d8];
        }
        __syncthreads();

        // ---- QK^T: fp16x3
        f32x4 sacc[4] = {{0,0,0,0},{0,0,0,0},{0,0,0,0},{0,0,0,0}};
#pragma unroll
        for (int ks = 0; ks < 2; ++ks)
#pragma unroll
          for (int kt4 = 0; kt4 < 4; ++kt4) {
            const int ba = SW(kt4 * 16 + (lane & 15), ks * 32 + (lane >> 4) * 8);
            f16x8 bh = *(const f16x8*)&Ksh[ba];
            f16x8 bl = *(const f16x8*)&Ksl[ba];
            sacc[kt4] = MFMA16(qhf[ks], bh, sacc[kt4], 0, 0, 0);
            sacc[kt4] = MFMA16(qlf[ks], bh, sacc[kt4], 0, 0, 0);
            sacc[kt4] = MFMA16(qhf[ks], bl, sacc[kt4], 0, 0, 0);
          }

        // ---- causal mask on the diagonal tile
        if (kt == qb) {
#pragma unroll
          for (int kt4 = 0; kt4 < 4; ++kt4) {
            const int key = j0 + kt4 * 16 + (lane & 15);
#pragma unroll
            for (int r = 0; r < 4; ++r)
              if (key > qrow0 + (lane >> 4) * 4 + r) sacc[kt4][r] = -INFINITY;
          }
        }

        // ---- online softmax (exp2 domain), P -> LDS f16
        float alf[4];
#pragma unroll
        for (int r = 0; r < 4; ++r) {
          float mx = fmaxf(fmaxf(sacc[0][r], sacc[1][r]),
                           fmaxf(sacc[2][r], sacc[3][r]));
          mx = fmaxf(mx, __shfl_xor(mx, 1));
          mx = fmaxf(mx, __shfl_xor(mx, 2));
          mx = fmaxf(mx, __shfl_xor(mx, 4));
          mx = fmaxf(mx, __shfl_xor(mx, 8));
          const float mn = fmaxf(m[r], mx);
          const float al = exp2f(m[r] - mn);
          const int prow = w * 16 + (lane >> 4) * 4 + r;
          float ps = 0.f;
#pragma unroll
          for (int kt4 = 0; kt4 < 4; ++kt4) {
            const _Float16 ph = (_Float16)exp2f(sacc[kt4][r] - mn);
            ps += (float)ph;
            Pt[SW(prow, kt4 * 16 + (lane & 15))] = ph;
          }
          ps += __shfl_xor(ps, 1);
          ps += __shfl_xor(ps, 2);
          ps += __shfl_xor(ps, 4);
          ps += __shfl_xor(ps, 8);
          lsum[r] = lsum[r] * al + ps;
          m[r] = mn;
          alf[r] = al;
        }
        const f32x4 av = {alf[0], alf[1], alf[2], alf[3]};
#pragma unroll
        for (int ct = 0; ct < 4; ++ct) o[ct] *= av;

        // ---- PV (per-wave Pt region)
#pragma unroll
        for (int ks = 0; ks < 2; ++ks) {
          f16x8 pa = *(const f16x8*)&Pt[SW(w * 16 + (lane & 15),
                                           ks * 32 + (lane >> 4) * 8)];
#pragma unroll
          for (int ct = 0; ct < 4; ++ct) {
            f16x8 vb = *(const f16x8*)&Vs[SW(ct * 16 + (lane & 15),
                                             ks * 32 + (lane >> 4) * 8)];
            o[ct] = MFMA16(pa, vb, o[ct], 0, 0, 0);
          }
        }
      }
    }

    // ---- write partials: normalized o (f16) + (m, l) f32
    f32x4 invv;
#pragma unroll
    for (int r = 0; r < 4; ++r) invv[r] = (nt > 0) ? 1.0f / lsum[r] : 0.0f;
    const size_t ridx0 = (size_t)(b * NSPLIT + s) * SEQ + qrow0 + (lane >> 4) * 4;
#pragma unroll
    for (int ct = 0; ct < 4; ++ct)
#pragma unroll
      for (int r = 0; r < 4; ++r)
        opart[(ridx0 + r) * HD + ct * 16 + (lane & 15)] =
            (_Float16)(o[ct][r] * invv[r]);
    if ((lane & 15) == 0) {
#pragma unroll
      for (int r = 0; r < 4; ++r) {
        mlp[(ridx0 + r) * 2]     = m[r];
        mlp[(ridx0 + r) * 2 + 1] = lsum[r];
      }
    }
  }
}

// ---------- combine the 4 kv-parity partials -------------------------------
__global__ __launch_bounds__(256) void combine_kernel(
    const _Float16* __restrict__ opart, const float* __restrict__ mlp,
    float* __restrict__ out)
{
  const int g = blockIdx.x * 256 + threadIdx.x;   // 262144
  const int row = g >> 4;
  const int cq = (g & 15) * 4;
  const int b = row >> 12, pos = row & 4095;

  float mv[4], lv[4], msx = -INFINITY;
#pragma unroll
  for (int s = 0; s < 4; ++s) {
    const size_t ri = (size_t)(b * NSPLIT + s) * SEQ + pos;
    mv[s] = mlp[ri * 2];
    lv[s] = mlp[ri * 2 + 1];
    msx = fmaxf(msx, mv[s]);
  }
  f32x4 num = {0.f, 0.f, 0.f, 0.f};
  float L = 0.f;
#pragma unroll
  for (int s = 0; s < 4; ++s) {
    const float wgt = lv[s] * exp2f(mv[s] - msx);
    L += wgt;
    const size_t ri = (size_t)(b * NSPLIT + s) * SEQ + pos;
    const f16x4 ov = *(const f16x4*)&opart[ri * HD + cq];
#pragma unroll
    for (int j = 0; j < 4; ++j) num[j] += wgt * (float)ov[j];
  }
  const float inv = 1.0f / L;
  f32x4 res = {num[0] * inv, num[1] * inv, num[2] * inv, num[3] * inv};
  *(f32x4*)&out[(size_t)row * HD + cq] = res;
}

extern "C" void kernel_launch(void* const* d_in, const int* in_sizes, int n_in,
                              void* d_out, int out_size, void* d_ws, size_t ws_size,
                              hipStream_t stream) {
  const float* query = (const float*)d_in[0];
  const float* key   = (const float*)d_in[1];
  const float* value = (const float*)d_in[2];
  const float* Wq    = (const float*)d_in[3];
  const float* Wk    = (const float*)d_in[4];
  const float* Wv    = (const float*)d_in[5];
  // d_in[6]: causal mask, handled analytically.

  float* out = (float*)d_out;

  _Float16* qh  = (_Float16*)d_ws;
  _Float16* ql  = qh  + (size_t)NB * SEQ * HD;
  _Float16* kh  = ql  + (size_t)NB * SEQ * HD;
  _Float16* kl  = kh  + (size_t)NB * SEQ * HD;
  _Float16* vt  = kl  + (size_t)NB * SEQ * HD;           // [b][64][4096]
  _Float16* wth = vt  + (size_t)NB * SEQ * HD;           // [3][64][1024]
  _Float16* wtl = wth + (size_t)3 * HD * DIM;
  _Float16* opart = wtl + (size_t)3 * HD * DIM;          // [b*4+s][4096][64]
  float* mlp = (float*)(opart + (size_t)NB * NSPLIT * SEQ * HD);

  wsplit_kernel<<<dim3(3, 64), 256, 0, stream>>>(Wq, Wk, Wv, wth, wtl);
  proj_kernel<<<dim3(256, 3), 256, 0, stream>>>(query, key, value, wth, wtl,
                                                qh, ql, kh, kl, vt);
  attn_kernel<<<dim3(128, NB), 256, 0, stream>>>(qh, ql, kh, kl, vt, opart, mlp);
  combine_kernel<<<1024, 256, 0, stream>>>(opart, mlp, out);
}

// Round 4
// 153.782 us; speedup vs baseline: 3.3897x; 1.0171x over previous
//
#include <hip/hip_runtime.h>
#include <math.h>

// HeadAttention B=4, S=4096, D=1024, DK=DV=64, fp32 in/out, causal.
// Round 4: proj latency fix. R3 proj was VGPR-starved (48 regs) -> 16 W
// L2-loads serialized in the MFMA chain (~6k cyc/K-tile). Now:
//  - __launch_bounds__(256,2): VGPR cap 256
//  - W fragments double-buffered in registers (load kt+1 while computing kt)
//  - NO __syncthreads in the K-loop: each wave reads only LDS it staged
//    itself, so per-wave s_waitcnt vmcnt(0) (+sched_barrier) suffices and
//    waves slip freely (no all-wave barrier drain).
// Attention / combine / wsplit unchanged from round 3 (passed, ~33us).

#define SEQ 4096
#define DIM 1024
#define HD  64
#define NB  4
#define NSPLIT 4

typedef __attribute__((ext_vector_type(4))) float    f32x4;
typedef __attribute__((ext_vector_type(8))) _Float16 f16x8;
typedef __attribute__((ext_vector_type(4))) _Float16 f16x4;

#define MFMA16 __builtin_amdgcn_mfma_f32_16x16x32_f16

// async 16B global->LDS (linear dest: wave-uniform base + lane*16)
#define GLOAD_LDS16(g, l)                                          \
  __builtin_amdgcn_global_load_lds(                                \
      (const __attribute__((address_space(1))) void*)(g),          \
      (__attribute__((address_space(3))) void*)(l), 16, 0, 0)

// per-wave VMEM drain; "memory" clobber orders LDS reads, sched_barrier
// pins register-only consumers (rule #18)
#define VWAIT() do { asm volatile("s_waitcnt vmcnt(0)" ::: "memory"); \
  __builtin_amdgcn_sched_barrier(0); } while (0)

// swizzled offset into a [row][64] f16 LDS tile (attn): XOR 16B-chunk with row&7
__device__ __forceinline__ int SW(int row, int k) {
  return row * 64 + (k ^ ((row & 7) << 3));
}

// ---------- W pre-split: wt_h/wt_l[mat][col][k] f16, Wq scaled by log2e/8 --
__global__ __launch_bounds__(256) void wsplit_kernel(
    const float* __restrict__ Wq, const float* __restrict__ Wk,
    const float* __restrict__ Wv, _Float16* __restrict__ wth,
    _Float16* __restrict__ wtl)
{
  const int mat = blockIdx.x;   // 0..2
  const int col = blockIdx.y;   // 0..63
  const float* __restrict__ W = (mat == 0) ? Wq : (mat == 1) ? Wk : Wv;
  const float scale = (mat == 0) ? 0.18033688011112042f : 1.0f;  // log2(e)/8
  const size_t base = ((size_t)mat * HD + col) * DIM;
#pragma unroll
  for (int u = 0; u < 4; ++u) {
    const int k = threadIdx.x + u * 256;
    const float y = W[(size_t)k * HD + col] * scale;
    const _Float16 h = (_Float16)y;
    wth[base + k] = h;
    wtl[base + k] = (_Float16)(y - (float)h);
  }
}

// ---------- projection: LDS-staged fp16x3 MFMA, per-wave pipeline ----------
// grid (256, 3), 256 threads (4 waves x 16 rows). Y = X[16384,1024]@W[1024,64]
__global__ __launch_bounds__(256, 2) void proj_kernel(
    const float* __restrict__ Xq, const float* __restrict__ Xk,
    const float* __restrict__ Xv,
    const _Float16* __restrict__ wth, const _Float16* __restrict__ wtl,
    _Float16* __restrict__ qh, _Float16* __restrict__ ql,
    _Float16* __restrict__ kh, _Float16* __restrict__ kl,
    _Float16* __restrict__ vt)
{
  __shared__ __attribute__((aligned(16))) float Xs[2][64 * 64];

  const int which = blockIdx.y;
  const float* __restrict__ X = (which == 0) ? Xq : (which == 1) ? Xk : Xv;

  const int t = threadIdx.x, lane = t & 63, w = t >> 6;
  const int bm = blockIdx.x * 64;

  // staging: thread handles chunks c = (w*4+i)*64 + lane (16B units);
  // row = c>>4, cc = lane&15, source chunk = cc ^ (row&15) (read-side XOR
  // matches -> conflict-free ds_read_b128). Wave w stages and consumes ONLY
  // rows w*16..w*16+15 -> no inter-wave LDS dependency -> no barrier needed.
  const float* gsrc[4];
  int lofs[4];
#pragma unroll
  for (int i = 0; i < 4; ++i) {
    const int row = w * 16 + i * 4 + (lane >> 4);
    const int srcc = (lane & 15) ^ (row & 15);
    gsrc[i] = X + (size_t)(bm + row) * DIM + srcc * 4;
    lofs[i] = (w * 4 + i) * 256;
  }

  // W fragment base (B-operand: col = lane&15, k = (lane>>4)*8)
  const size_t wb = ((size_t)which * HD + (lane & 15)) * DIM + ((lane >> 4) * 8);
  const _Float16* wbh = wth + wb;
  const _Float16* wbl = wtl + wb;

  const int frow = lane & 15;
  const int ldsrow = w * 16 + frow;

  f32x4 acc[4] = {{0,0,0,0},{0,0,0,0},{0,0,0,0},{0,0,0,0}};
  f16x8 wAh[8], wAl[8], wBh[8], wBl[8];

  auto stage = [&](int kt, int buf) {
#pragma unroll
    for (int i = 0; i < 4; ++i)
      GLOAD_LDS16(gsrc[i] + kt * 64, &Xs[buf][lofs[i]]);
  };
  auto loadW = [&](int kt, f16x8* wh, f16x8* wl) {
    const size_t ko = (size_t)kt * 64;
#pragma unroll
    for (int ks = 0; ks < 2; ++ks)
#pragma unroll
      for (int ct = 0; ct < 4; ++ct) {
        wh[ks * 4 + ct] = *(const f16x8*)(wbh + (size_t)ct * 16 * DIM + ko + ks * 32);
        wl[ks * 4 + ct] = *(const f16x8*)(wbl + (size_t)ct * 16 * DIM + ko + ks * 32);
      }
  };
  auto compute = [&](const float* xt, const f16x8* wh, const f16x8* wl) {
#pragma unroll
    for (int ks = 0; ks < 2; ++ks) {
      const int cc0 = ks * 8 + (lane >> 4) * 2;
      f32x4 x0 = *(const f32x4*)&xt[ldsrow * 64 + ((cc0 ^ frow) * 4)];
      f32x4 x1 = *(const f32x4*)&xt[ldsrow * 64 + (((cc0 + 1) ^ frow) * 4)];
      f16x8 xh, xl;
#pragma unroll
      for (int j = 0; j < 4; ++j) {
        const _Float16 h = (_Float16)x0[j];
        xh[j] = h; xl[j] = (_Float16)(x0[j] - (float)h);
      }
#pragma unroll
      for (int j = 0; j < 4; ++j) {
        const _Float16 h = (_Float16)x1[j];
        xh[j + 4] = h; xl[j + 4] = (_Float16)(x1[j] - (float)h);
      }
#pragma unroll
      for (int ct = 0; ct < 4; ++ct) {
        acc[ct] = MFMA16(xh, wh[ks * 4 + ct], acc[ct], 0, 0, 0);
        acc[ct] = MFMA16(xl, wh[ks * 4 + ct], acc[ct], 0, 0, 0);
        acc[ct] = MFMA16(xh, wl[ks * 4 + ct], acc[ct], 0, 0, 0);
      }
    }
  };

  // prologue: tile 0 in flight
  stage(0, 0);
  loadW(0, wAh, wAl);

  for (int kt2 = 0; kt2 < DIM / 64; kt2 += 2) {
    // even tile kt2: wait S(kt2)+W(kt2); issue kt2+1; compute from buf0/wA
    VWAIT();
    stage(kt2 + 1, 1);
    loadW(kt2 + 1, wBh, wBl);
    compute(&Xs[0][0], wAh, wAl);
    // odd tile kt2+1: wait; issue kt2+2; compute from buf1/wB
    VWAIT();
    if (kt2 + 2 < DIM / 64) {
      stage(kt2 + 2, 0);
      loadW(kt2 + 2, wAh, wAl);
    }
    compute(&Xs[1][0], wBh, wBl);
  }

  // epilogue: C layout col=lane&15, row=(lane>>4)*4+r
  const size_t orow0 = (size_t)bm + w * 16 + (lane >> 4) * 4;
  if (which < 2) {
    _Float16* oh = (which == 0) ? qh : kh;
    _Float16* ol = (which == 0) ? ql : kl;
#pragma unroll
    for (int ct = 0; ct < 4; ++ct)
#pragma unroll
      for (int r = 0; r < 4; ++r) {
        const float y = acc[ct][r];
        const _Float16 h = (_Float16)y;
        const size_t idx = (orow0 + r) * HD + ct * 16 + (lane & 15);
        oh[idx] = h;
        ol[idx] = (_Float16)(y - (float)h);
      }
  } else {
    const int batch = (int)(orow0 >> 12);
    const int pos = (int)(orow0 & 4095);
#pragma unroll
    for (int ct = 0; ct < 4; ++ct) {
      f16x4 hv;
#pragma unroll
      for (int r = 0; r < 4; ++r) hv[r] = (_Float16)acc[ct][r];
      *(f16x4*)&vt[((size_t)batch * HD + ct * 16 + (lane & 15)) * SEQ + pos] = hv;
    }
  }
}

// ---------- flash attention, fp16x3 QK + f16 PV, split-4 partials ----------
// grid (128, 4): x -> pair p=x>>2 (q-blocks p and 63-p), parity s=x&3.
__global__ __launch_bounds__(256) void attn_kernel(
    const _Float16* __restrict__ qh, const _Float16* __restrict__ ql,
    const _Float16* __restrict__ kh, const _Float16* __restrict__ kl,
    const _Float16* __restrict__ vt,
    _Float16* __restrict__ opart, float* __restrict__ mlp)
{
  __shared__ __attribute__((aligned(16))) _Float16 Ksh[64 * 64];
  __shared__ __attribute__((aligned(16))) _Float16 Ksl[64 * 64];
  __shared__ __attribute__((aligned(16))) _Float16 Vs [64 * 64];
  __shared__ __attribute__((aligned(16))) _Float16 Pt [64 * 64];

  const int t = threadIdx.x, lane = t & 63, w = t >> 6;
  const int b = blockIdx.y;
  const int p = blockIdx.x >> 2, s = blockIdx.x & 3;
  const size_t bS = (size_t)b * SEQ;

  for (int sel = 0; sel < 2; ++sel) {
    const int qb = sel ? (63 - p) : p;
    const int qrow0 = qb * 64 + w * 16;
    const int nt = (qb >= s) ? ((qb - s) >> 2) + 1 : 0;  // kv tiles ≡ s mod 4

    float m[4] = {-INFINITY, -INFINITY, -INFINITY, -INFINITY};
    float lsum[4] = {0.f, 0.f, 0.f, 0.f};
    f32x4 o[4] = {{0,0,0,0},{0,0,0,0},{0,0,0,0},{0,0,0,0}};

    if (nt > 0) {
      const _Float16* qhp = qh + (bS + qrow0 + (lane & 15)) * HD + ((lane >> 4) * 8);
      const _Float16* qlp = ql + (bS + qrow0 + (lane & 15)) * HD + ((lane >> 4) * 8);
      f16x8 qhf[2], qlf[2];
      qhf[0] = *(const f16x8*)(qhp);      qhf[1] = *(const f16x8*)(qhp + 32);
      qlf[0] = *(const f16x8*)(qlp);      qlf[1] = *(const f16x8*)(qlp + 32);

      for (int i = 0; i < nt; ++i) {
        const int kt = s + 4 * i;
        const int j0 = kt * 64;

        __syncthreads();  // previous tile's LDS reads complete
#pragma unroll
        for (int c = 0; c < 2; ++c) {
          const int lin = t + 256 * c;
          const int row = lin >> 3, d8 = (lin & 7) * 8;
          const int dst = SW(row, d8);
          *(f16x8*)&Ksh[dst] = *(const f16x8*)&kh[(bS + j0 + row) * HD + d8];
          *(f16x8*)&Ksl[dst] = *(const f16x8*)&kl[(bS + j0 + row) * HD + d8];
          *(f16x8*)&Vs[dst]  = *(const f16x8*)&vt[((size_t)b * HD + row) * SEQ + j0 + d8];
        }
        __syncthreads();

        // ---- QK^T: fp16x3
        f32x4 sacc[4] = {{0,0,0,0},{0,0,0,0},{0,0,0,0},{0,0,0,0}};
#pragma unroll
        for (int ks = 0; ks < 2; ++ks)
#pragma unroll
          for (int kt4 = 0; kt4 < 4; ++kt4) {
            const int ba = SW(kt4 * 16 + (lane & 15), ks * 32 + (lane >> 4) * 8);
            f16x8 bh = *(const f16x8*)&Ksh[ba];
            f16x8 bl = *(const f16x8*)&Ksl[ba];
            sacc[kt4] = MFMA16(qhf[ks], bh, sacc[kt4], 0, 0, 0);
            sacc[kt4] = MFMA16(qlf[ks], bh, sacc[kt4], 0, 0, 0);
            sacc[kt4] = MFMA16(qhf[ks], bl, sacc[kt4], 0, 0, 0);
          }

        // ---- causal mask on the diagonal tile
        if (kt == qb) {
#pragma unroll
          for (int kt4 = 0; kt4 < 4; ++kt4) {
            const int key = j0 + kt4 * 16 + (lane & 15);
#pragma unroll
            for (int r = 0; r < 4; ++r)
              if (key > qrow0 + (lane >> 4) * 4 + r) sacc[kt4][r] = -INFINITY;
          }
        }

        // ---- online softmax (exp2 domain), P -> LDS f16
        float alf[4];
#pragma unroll
        for (int r = 0; r < 4; ++r) {
          float mx = fmaxf(fmaxf(sacc[0][r], sacc[1][r]),
                           fmaxf(sacc[2][r], sacc[3][r]));
          mx = fmaxf(mx, __shfl_xor(mx, 1));
          mx = fmaxf(mx, __shfl_xor(mx, 2));
          mx = fmaxf(mx, __shfl_xor(mx, 4));
          mx = fmaxf(mx, __shfl_xor(mx, 8));
          const float mn = fmaxf(m[r], mx);
          const float al = exp2f(m[r] - mn);
          const int prow = w * 16 + (lane >> 4) * 4 + r;
          float ps = 0.f;
#pragma unroll
          for (int kt4 = 0; kt4 < 4; ++kt4) {
            const _Float16 ph = (_Float16)exp2f(sacc[kt4][r] - mn);
            ps += (float)ph;
            Pt[SW(prow, kt4 * 16 + (lane & 15))] = ph;
          }
          ps += __shfl_xor(ps, 1);
          ps += __shfl_xor(ps, 2);
          ps += __shfl_xor(ps, 4);
          ps += __shfl_xor(ps, 8);
          lsum[r] = lsum[r] * al + ps;
          m[r] = mn;
          alf[r] = al;
        }
        const f32x4 av = {alf[0], alf[1], alf[2], alf[3]};
#pragma unroll
        for (int ct = 0; ct < 4; ++ct) o[ct] *= av;

        // ---- PV (per-wave Pt region)
#pragma unroll
        for (int ks = 0; ks < 2; ++ks) {
          f16x8 pa = *(const f16x8*)&Pt[SW(w * 16 + (lane & 15),
                                           ks * 32 + (lane >> 4) * 8)];
#pragma unroll
          for (int ct = 0; ct < 4; ++ct) {
            f16x8 vb = *(const f16x8*)&Vs[SW(ct * 16 + (lane & 15),
                                             ks * 32 + (lane >> 4) * 8)];
            o[ct] = MFMA16(pa, vb, o[ct], 0, 0, 0);
          }
        }
      }
    }

    // ---- write partials: normalized o (f16) + (m, l) f32
    f32x4 invv;
#pragma unroll
    for (int r = 0; r < 4; ++r) invv[r] = (nt > 0) ? 1.0f / lsum[r] : 0.0f;
    const size_t ridx0 = (size_t)(b * NSPLIT + s) * SEQ + qrow0 + (lane >> 4) * 4;
#pragma unroll
    for (int ct = 0; ct < 4; ++ct)
#pragma unroll
      for (int r = 0; r < 4; ++r)
        opart[(ridx0 + r) * HD + ct * 16 + (lane & 15)] =
            (_Float16)(o[ct][r] * invv[r]);
    if ((lane & 15) == 0) {
#pragma unroll
      for (int r = 0; r < 4; ++r) {
        mlp[(ridx0 + r) * 2]     = m[r];
        mlp[(ridx0 + r) * 2 + 1] = lsum[r];
      }
    }
  }
}

// ---------- combine the 4 kv-parity partials -------------------------------
__global__ __launch_bounds__(256) void combine_kernel(
    const _Float16* __restrict__ opart, const float* __restrict__ mlp,
    float* __restrict__ out)
{
  const int g = blockIdx.x * 256 + threadIdx.x;   // 262144
  const int row = g >> 4;
  const int cq = (g & 15) * 4;
  const int b = row >> 12, pos = row & 4095;

  float mv[4], lv[4], msx = -INFINITY;
#pragma unroll
  for (int s = 0; s < 4; ++s) {
    const size_t ri = (size_t)(b * NSPLIT + s) * SEQ + pos;
    mv[s] = mlp[ri * 2];
    lv[s] = mlp[ri * 2 + 1];
    msx = fmaxf(msx, mv[s]);
  }
  f32x4 num = {0.f, 0.f, 0.f, 0.f};
  float L = 0.f;
#pragma unroll
  for (int s = 0; s < 4; ++s) {
    const float wgt = lv[s] * exp2f(mv[s] - msx);
    L += wgt;
    const size_t ri = (size_t)(b * NSPLIT + s) * SEQ + pos;
    const f16x4 ov = *(const f16x4*)&opart[ri * HD + cq];
#pragma unroll
    for (int j = 0; j < 4; ++j) num[j] += wgt * (float)ov[j];
  }
  const float inv = 1.0f / L;
  f32x4 res = {num[0] * inv, num[1] * inv, num[2] * inv, num[3] * inv};
  *(f32x4*)&out[(size_t)row * HD + cq] = res;
}

extern "C" void kernel_launch(void* const* d_in, const int* in_sizes, int n_in,
                              void* d_out, int out_size, void* d_ws, size_t ws_size,
                              hipStream_t stream) {
  const float* query = (const float*)d_in[0];
  const float* key   = (const float*)d_in[1];
  const float* value = (const float*)d_in[2];
  const float* Wq    = (const float*)d_in[3];
  const float* Wk    = (const float*)d_in[4];
  const float* Wv    = (const float*)d_in[5];
  // d_in[6]: causal mask, handled analytically.

  float* out = (float*)d_out;

  _Float16* qh  = (_Float16*)d_ws;
  _Float16* ql  = qh  + (size_t)NB * SEQ * HD;
  _Float16* kh  = ql  + (size_t)NB * SEQ * HD;
  _Float16* kl  = kh  + (size_t)NB * SEQ * HD;
  _Float16* vt  = kl  + (size_t)NB * SEQ * HD;           // [b][64][4096]
  _Float16* wth = vt  + (size_t)NB * SEQ * HD;           // [3][64][1024]
  _Float16* wtl = wth + (size_t)3 * HD * DIM;
  _Float16* opart = wtl + (size_t)3 * HD * DIM;          // [b*4+s][4096][64]
  float* mlp = (float*)(opart + (size_t)NB * NSPLIT * SEQ * HD);

  wsplit_kernel<<<dim3(3, 64), 256, 0, stream>>>(Wq, Wk, Wv, wth, wtl);
  proj_kernel<<<dim3(256, 3), 256, 0, stream>>>(query, key, value, wth, wtl,
                                                qh, ql, kh, kl, vt);
  attn_kernel<<<dim3(128, NB), 256, 0, stream>>>(qh, ql, kh, kl, vt, opart, mlp);
  combine_kernel<<<1024, 256, 0, stream>>>(opart, mlp, out);
}

// Round 5
// 112.175 us; speedup vs baseline: 4.6470x; 1.3709x over previous
//
#include <hip/hip_runtime.h>
#include <math.h>

// HeadAttention B=4, S=4096, D=1024, DK=DV=64, fp32 in/out, causal.
// Round 5: proj back to the proven m97 structure — BOTH operands staged via
// global_load_lds + one __syncthreads per K-step. R3/R4 per-lane W loads were
// latency-serialized (VGPR allocator refused the register pipeline, VGPR=100
// < the 128 needed). wsplit now emits W in fragment-linear layout so a W
// K-tile stages as a 16 KB contiguous copy; frag reads are ds_read_b128 at
// lane*16 (conflict-free). No per-lane global loads in the K-loop at all.
// Attention / combine unchanged (passed, ~33us combined).

#define SEQ 4096
#define DIM 1024
#define HD  64
#define NB  4
#define NSPLIT 4

typedef __attribute__((ext_vector_type(4))) float    f32x4;
typedef __attribute__((ext_vector_type(8))) _Float16 f16x8;
typedef __attribute__((ext_vector_type(4))) _Float16 f16x4;

#define MFMA16 __builtin_amdgcn_mfma_f32_16x16x32_f16

// async 16B global->LDS (linear dest: wave-uniform base + lane*16; global
// source is per-lane)
#define GLOAD_LDS16(g, l)                                          \
  __builtin_amdgcn_global_load_lds(                                \
      (const __attribute__((address_space(1))) void*)(g),          \
      (__attribute__((address_space(3))) void*)(l), 16, 0, 0)

// swizzled offset into a [row][64] f16 LDS tile (attn): XOR 16B-chunk with row&7
__device__ __forceinline__ int SW(int row, int k) {
  return row * 64 + (k ^ ((row & 7) << 3));
}

// ---------- W pre-split into fragment-linear layout ------------------------
// wf[((which*16+kt)*16 + slot)*512 + lane*8 + j]:
//   slot s=ks*4+ct (0..7) hi-frag, s+8 lo-frag;
//   element = W[k][col]*scale, col=ct*16+(lane&15), k=kt*64+ks*32+(lane>>4)*8+j
// (mapping derived 1:1 from the round-4 loadW, which validated.)
__global__ __launch_bounds__(256) void wsplit_kernel(
    const float* __restrict__ Wq, const float* __restrict__ Wk,
    const float* __restrict__ Wv, _Float16* __restrict__ wf)
{
  const int which = blockIdx.x;   // 0..2
  const int kt    = blockIdx.y;   // 0..15
  const float* __restrict__ W = (which == 0) ? Wq : (which == 1) ? Wk : Wv;
  const float scale = (which == 0) ? 0.18033688011112042f : 1.0f;  // log2(e)/8
  const size_t tb = ((size_t)which * 16 + kt) * 8192;
#pragma unroll
  for (int i = 0; i < 2; ++i) {
    const int pair = threadIdx.x + 256 * i;   // 0..511
    const int lane = pair & 63, f = pair >> 6;  // f = ks*4+ct in 0..7
    const int ks = f >> 2, ct = f & 3;
    const int col = ct * 16 + (lane & 15);
    const int k0 = kt * 64 + ks * 32 + (lane >> 4) * 8;
    f16x8 hv, lv;
#pragma unroll
    for (int j = 0; j < 8; ++j) {
      const float y = W[(size_t)(k0 + j) * HD + col] * scale;
      const _Float16 h = (_Float16)y;
      hv[j] = h;
      lv[j] = (_Float16)(y - (float)h);
    }
    *(f16x8*)&wf[tb + (size_t)f * 512 + lane * 8]       = hv;
    *(f16x8*)&wf[tb + (size_t)(8 + f) * 512 + lane * 8] = lv;
  }
}

// ---------- projection: m97-style, X+W LDS-staged fp16x3 MFMA --------------
// grid (256, 3), 256 threads (4 waves x 16 rows). Y = X[16384,1024]@W[1024,64]
// Per K-step: 8 global_load_lds (X 4 + W 4), 1 barrier, 20 ds_read_b128,
// 24 MFMA. LDS 64 KB -> 2 blocks/CU.
__global__ __launch_bounds__(256, 2) void proj_kernel(
    const float* __restrict__ Xq, const float* __restrict__ Xk,
    const float* __restrict__ Xv,
    const _Float16* __restrict__ wf,
    _Float16* __restrict__ qh, _Float16* __restrict__ ql,
    _Float16* __restrict__ kh, _Float16* __restrict__ kl,
    _Float16* __restrict__ vt)
{
  __shared__ __attribute__((aligned(16))) float    Xs[2][64 * 64];  // 16 KB ea
  __shared__ __attribute__((aligned(16))) _Float16 Ws[2][8192];     // 16 KB ea

  const int which = blockIdx.y;
  const float* __restrict__ X = (which == 0) ? Xq : (which == 1) ? Xk : Xv;

  const int t = threadIdx.x, lane = t & 63, w = t >> 6;
  const int bm = blockIdx.x * 64;

  // X staging: chunk c=(w*4+i)*64+lane; row=c>>4, cc=lane&15,
  // source chunk cc^(row&15); read side applies same XOR -> conflict-free.
  const float* gX[4];
  int lofs[4];
#pragma unroll
  for (int i = 0; i < 4; ++i) {
    const int row = w * 16 + i * 4 + (lane >> 4);
    const int srcc = (lane & 15) ^ (row & 15);
    gX[i] = X + (size_t)(bm + row) * DIM + srcc * 4;
    lofs[i] = (w * 4 + i) * 256;
  }
  // W staging: fully linear 16 KB tile copy
  const _Float16* gW[4];
  int wofs[4];
#pragma unroll
  for (int i = 0; i < 4; ++i) {
    gW[i] = wf + (size_t)which * 16 * 8192 + (w * 4 + i) * 512 + lane * 8;
    wofs[i] = (w * 4 + i) * 512;
  }

  const int frow = lane & 15;
  const int ldsrow = w * 16 + frow;

  f32x4 acc[4] = {{0,0,0,0},{0,0,0,0},{0,0,0,0},{0,0,0,0}};

  auto stage = [&](int kt, int buf) {
#pragma unroll
    for (int i = 0; i < 4; ++i)
      GLOAD_LDS16(gX[i] + kt * 64, &Xs[buf][lofs[i]]);
#pragma unroll
    for (int i = 0; i < 4; ++i)
      GLOAD_LDS16(gW[i] + (size_t)kt * 8192, &Ws[buf][wofs[i]]);
  };
  auto compute = [&](int buf) {
#pragma unroll
    for (int ks = 0; ks < 2; ++ks) {
      const int cc0 = ks * 8 + (lane >> 4) * 2;
      f32x4 x0 = *(const f32x4*)&Xs[buf][ldsrow * 64 + ((cc0 ^ frow) * 4)];
      f32x4 x1 = *(const f32x4*)&Xs[buf][ldsrow * 64 + (((cc0 + 1) ^ frow) * 4)];
      f16x8 xh, xl;
#pragma unroll
      for (int j = 0; j < 4; ++j) {
        const _Float16 h = (_Float16)x0[j];
        xh[j] = h; xl[j] = (_Float16)(x0[j] - (float)h);
      }
#pragma unroll
      for (int j = 0; j < 4; ++j) {
        const _Float16 h = (_Float16)x1[j];
        xh[j + 4] = h; xl[j + 4] = (_Float16)(x1[j] - (float)h);
      }
#pragma unroll
      for (int ct = 0; ct < 4; ++ct) {
        f16x8 bh = *(const f16x8*)&Ws[buf][(ks * 4 + ct) * 512 + lane * 8];
        f16x8 bl = *(const f16x8*)&Ws[buf][(8 + ks * 4 + ct) * 512 + lane * 8];
        acc[ct] = MFMA16(xh, bh, acc[ct], 0, 0, 0);
        acc[ct] = MFMA16(xl, bh, acc[ct], 0, 0, 0);
        acc[ct] = MFMA16(xh, bl, acc[ct], 0, 0, 0);
      }
    }
  };

  stage(0, 0);
  int cur = 0;
  for (int kt = 0; kt < DIM / 64; ++kt) {
    __syncthreads();            // buf[cur] staged; all waves done with buf[cur^1]
    if (kt + 1 < DIM / 64) stage(kt + 1, cur ^ 1);
    compute(cur);
    cur ^= 1;
  }

  // epilogue: C layout col=lane&15, row=(lane>>4)*4+r
  const size_t orow0 = (size_t)bm + w * 16 + (lane >> 4) * 4;
  if (which < 2) {
    _Float16* oh = (which == 0) ? qh : kh;
    _Float16* ol = (which == 0) ? ql : kl;
#pragma unroll
    for (int ct = 0; ct < 4; ++ct)
#pragma unroll
      for (int r = 0; r < 4; ++r) {
        const float y = acc[ct][r];
        const _Float16 h = (_Float16)y;
        const size_t idx = (orow0 + r) * HD + ct * 16 + (lane & 15);
        oh[idx] = h;
        ol[idx] = (_Float16)(y - (float)h);
      }
  } else {
    const int batch = (int)(orow0 >> 12);
    const int pos = (int)(orow0 & 4095);
#pragma unroll
    for (int ct = 0; ct < 4; ++ct) {
      f16x4 hv;
#pragma unroll
      for (int r = 0; r < 4; ++r) hv[r] = (_Float16)acc[ct][r];
      *(f16x4*)&vt[((size_t)batch * HD + ct * 16 + (lane & 15)) * SEQ + pos] = hv;
    }
  }
}

// ---------- flash attention, fp16x3 QK + f16 PV, split-4 partials ----------
// grid (128, 4): x -> pair p=x>>2 (q-blocks p and 63-p), parity s=x&3.
__global__ __launch_bounds__(256) void attn_kernel(
    const _Float16* __restrict__ qh, const _Float16* __restrict__ ql,
    const _Float16* __restrict__ kh, const _Float16* __restrict__ kl,
    const _Float16* __restrict__ vt,
    _Float16* __restrict__ opart, float* __restrict__ mlp)
{
  __shared__ __attribute__((aligned(16))) _Float16 Ksh[64 * 64];
  __shared__ __attribute__((aligned(16))) _Float16 Ksl[64 * 64];
  __shared__ __attribute__((aligned(16))) _Float16 Vs [64 * 64];
  __shared__ __attribute__((aligned(16))) _Float16 Pt [64 * 64];

  const int t = threadIdx.x, lane = t & 63, w = t >> 6;
  const int b = blockIdx.y;
  const int p = blockIdx.x >> 2, s = blockIdx.x & 3;
  const size_t bS = (size_t)b * SEQ;

  for (int sel = 0; sel < 2; ++sel) {
    const int qb = sel ? (63 - p) : p;
    const int qrow0 = qb * 64 + w * 16;
    const int nt = (qb >= s) ? ((qb - s) >> 2) + 1 : 0;  // kv tiles ≡ s mod 4

    float m[4] = {-INFINITY, -INFINITY, -INFINITY, -INFINITY};
    float lsum[4] = {0.f, 0.f, 0.f, 0.f};
    f32x4 o[4] = {{0,0,0,0},{0,0,0,0},{0,0,0,0},{0,0,0,0}};

    if (nt > 0) {
      const _Float16* qhp = qh + (bS + qrow0 + (lane & 15)) * HD + ((lane >> 4) * 8);
      const _Float16* qlp = ql + (bS + qrow0 + (lane & 15)) * HD + ((lane >> 4) * 8);
      f16x8 qhf[2], qlf[2];
      qhf[0] = *(const f16x8*)(qhp);      qhf[1] = *(const f16x8*)(qhp + 32);
      qlf[0] = *(const f16x8*)(qlp);      qlf[1] = *(const f16x8*)(qlp + 32);

      for (int i = 0; i < nt; ++i) {
        const int kt = s + 4 * i;
        const int j0 = kt * 64;

        __syncthreads();  // previous tile's LDS reads complete
#pragma unroll
        for (int c = 0; c < 2; ++c) {
          const int lin = t + 256 * c;
          const int row = lin >> 3, d8 = (lin & 7) * 8;
          const int dst = SW(row, d8);
          *(f16x8*)&Ksh[dst] = *(const f16x8*)&kh[(bS + j0 + row) * HD + d8];
          *(f16x8*)&Ksl[dst] = *(const f16x8*)&kl[(bS + j0 + row) * HD + d8];
          *(f16x8*)&Vs[dst]  = *(const f16x8*)&vt[((size_t)b * HD + row) * SEQ + j0 + d8];
        }
        __syncthreads();

        // ---- QK^T: fp16x3
        f32x4 sacc[4] = {{0,0,0,0},{0,0,0,0},{0,0,0,0},{0,0,0,0}};
#pragma unroll
        for (int ks = 0; ks < 2; ++ks)
#pragma unroll
          for (int kt4 = 0; kt4 < 4; ++kt4) {
            const int ba = SW(kt4 * 16 + (lane & 15), ks * 32 + (lane >> 4) * 8);
            f16x8 bh = *(const f16x8*)&Ksh[ba];
            f16x8 bl = *(const f16x8*)&Ksl[ba];
            sacc[kt4] = MFMA16(qhf[ks], bh, sacc[kt4], 0, 0, 0);
            sacc[kt4] = MFMA16(qlf[ks], bh, sacc[kt4], 0, 0, 0);
            sacc[kt4] = MFMA16(qhf[ks], bl, sacc[kt4], 0, 0, 0);
          }

        // ---- causal mask on the diagonal tile
        if (kt == qb) {
#pragma unroll
          for (int kt4 = 0; kt4 < 4; ++kt4) {
            const int key = j0 + kt4 * 16 + (lane & 15);
#pragma unroll
            for (int r = 0; r < 4; ++r)
              if (key > qrow0 + (lane >> 4) * 4 + r) sacc[kt4][r] = -INFINITY;
          }
        }

        // ---- online softmax (exp2 domain), P -> LDS f16
        float alf[4];
#pragma unroll
        for (int r = 0; r < 4; ++r) {
          float mx = fmaxf(fmaxf(sacc[0][r], sacc[1][r]),
                           fmaxf(sacc[2][r], sacc[3][r]));
          mx = fmaxf(mx, __shfl_xor(mx, 1));
          mx = fmaxf(mx, __shfl_xor(mx, 2));
          mx = fmaxf(mx, __shfl_xor(mx, 4));
          mx = fmaxf(mx, __shfl_xor(mx, 8));
          const float mn = fmaxf(m[r], mx);
          const float al = exp2f(m[r] - mn);
          const int prow = w * 16 + (lane >> 4) * 4 + r;
          float ps = 0.f;
#pragma unroll
          for (int kt4 = 0; kt4 < 4; ++kt4) {
            const _Float16 ph = (_Float16)exp2f(sacc[kt4][r] - mn);
            ps += (float)ph;
            Pt[SW(prow, kt4 * 16 + (lane & 15))] = ph;
          }
          ps += __shfl_xor(ps, 1);
          ps += __shfl_xor(ps, 2);
          ps += __shfl_xor(ps, 4);
          ps += __shfl_xor(ps, 8);
          lsum[r] = lsum[r] * al + ps;
          m[r] = mn;
          alf[r] = al;
        }
        const f32x4 av = {alf[0], alf[1], alf[2], alf[3]};
#pragma unroll
        for (int ct = 0; ct < 4; ++ct) o[ct] *= av;

        // ---- PV (per-wave Pt region)
#pragma unroll
        for (int ks = 0; ks < 2; ++ks) {
          f16x8 pa = *(const f16x8*)&Pt[SW(w * 16 + (lane & 15),
                                           ks * 32 + (lane >> 4) * 8)];
#pragma unroll
          for (int ct = 0; ct < 4; ++ct) {
            f16x8 vb = *(const f16x8*)&Vs[SW(ct * 16 + (lane & 15),
                                             ks * 32 + (lane >> 4) * 8)];
            o[ct] = MFMA16(pa, vb, o[ct], 0, 0, 0);
          }
        }
      }
    }

    // ---- write partials: normalized o (f16) + (m, l) f32
    f32x4 invv;
#pragma unroll
    for (int r = 0; r < 4; ++r) invv[r] = (nt > 0) ? 1.0f / lsum[r] : 0.0f;
    const size_t ridx0 = (size_t)(b * NSPLIT + s) * SEQ + qrow0 + (lane >> 4) * 4;
#pragma unroll
    for (int ct = 0; ct < 4; ++ct)
#pragma unroll
      for (int r = 0; r < 4; ++r)
        opart[(ridx0 + r) * HD + ct * 16 + (lane & 15)] =
            (_Float16)(o[ct][r] * invv[r]);
    if ((lane & 15) == 0) {
#pragma unroll
      for (int r = 0; r < 4; ++r) {
        mlp[(ridx0 + r) * 2]     = m[r];
        mlp[(ridx0 + r) * 2 + 1] = lsum[r];
      }
    }
  }
}

// ---------- combine the 4 kv-parity partials -------------------------------
__global__ __launch_bounds__(256) void combine_kernel(
    const _Float16* __restrict__ opart, const float* __restrict__ mlp,
    float* __restrict__ out)
{
  const int g = blockIdx.x * 256 + threadIdx.x;   // 262144
  const int row = g >> 4;
  const int cq = (g & 15) * 4;
  const int b = row >> 12, pos = row & 4095;

  float mv[4], lv[4], msx = -INFINITY;
#pragma unroll
  for (int s = 0; s < 4; ++s) {
    const size_t ri = (size_t)(b * NSPLIT + s) * SEQ + pos;
    mv[s] = mlp[ri * 2];
    lv[s] = mlp[ri * 2 + 1];
    msx = fmaxf(msx, mv[s]);
  }
  f32x4 num = {0.f, 0.f, 0.f, 0.f};
  float L = 0.f;
#pragma unroll
  for (int s = 0; s < 4; ++s) {
    const float wgt = lv[s] * exp2f(mv[s] - msx);
    L += wgt;
    const size_t ri = (size_t)(b * NSPLIT + s) * SEQ + pos;
    const f16x4 ov = *(const f16x4*)&opart[ri * HD + cq];
#pragma unroll
    for (int j = 0; j < 4; ++j) num[j] += wgt * (float)ov[j];
  }
  const float inv = 1.0f / L;
  f32x4 res = {num[0] * inv, num[1] * inv, num[2] * inv, num[3] * inv};
  *(f32x4*)&out[(size_t)row * HD + cq] = res;
}

extern "C" void kernel_launch(void* const* d_in, const int* in_sizes, int n_in,
                              void* d_out, int out_size, void* d_ws, size_t ws_size,
                              hipStream_t stream) {
  const float* query = (const float*)d_in[0];
  const float* key   = (const float*)d_in[1];
  const float* value = (const float*)d_in[2];
  const float* Wq    = (const float*)d_in[3];
  const float* Wk    = (const float*)d_in[4];
  const float* Wv    = (const float*)d_in[5];
  // d_in[6]: causal mask, handled analytically.

  float* out = (float*)d_out;

  _Float16* qh  = (_Float16*)d_ws;
  _Float16* ql  = qh  + (size_t)NB * SEQ * HD;
  _Float16* kh  = ql  + (size_t)NB * SEQ * HD;
  _Float16* kl  = kh  + (size_t)NB * SEQ * HD;
  _Float16* vt  = kl  + (size_t)NB * SEQ * HD;           // [b][64][4096]
  _Float16* wf  = vt  + (size_t)NB * SEQ * HD;           // [3][16][16][512]
  _Float16* opart = wf + (size_t)3 * 16 * 8192;          // [b*4+s][4096][64]
  float* mlp = (float*)(opart + (size_t)NB * NSPLIT * SEQ * HD);

  wsplit_kernel<<<dim3(3, 16), 256, 0, stream>>>(Wq, Wk, Wv, wf);
  proj_kernel<<<dim3(256, 3), 256, 0, stream>>>(query, key, value, wf,
                                                qh, ql, kh, kl, vt);
  attn_kernel<<<dim3(128, NB), 256, 0, stream>>>(qh, ql, kh, kl, vt, opart, mlp);
  combine_kernel<<<1024, 256, 0, stream>>>(opart, mlp, out);
}

// Round 6
// 92.693 us; speedup vs baseline: 5.6237x; 1.2102x over previous
//
#include <hip/hip_runtime.h>
#include <math.h>

// HeadAttention B=4, S=4096, D=1024, DK=DV=64, fp32 in/out, causal.
// Round 6: proj staging moved OFF the LDS-DMA path. R5 (8 global_load_lds
// per thread per step + __syncthreads vmcnt(0) drain) delivered only
// 3.3 B/cy/CU (9.5k cy/step). Now: reg-staged (global->reg->ds_write, HK
// pattern), tile kt+1's loads issued before the barrier and NEVER drained
// by it (counted-wait discipline: only vmcnt(0) at top-of-iter after a
// full compute phase of flight time), ONE raw s_barrier per K-step.
// Attention / combine / wsplit unchanged (passed; ~17us combined).

#define SEQ 4096
#define DIM 1024
#define HD  64
#define NB  4
#define NSPLIT 4

typedef __attribute__((ext_vector_type(4))) float    f32x4;
typedef __attribute__((ext_vector_type(8))) _Float16 f16x8;
typedef __attribute__((ext_vector_type(4))) _Float16 f16x4;

#define MFMA16 __builtin_amdgcn_mfma_f32_16x16x32_f16

// swizzled offset into a [row][64] f16 LDS tile (attn): XOR 16B-chunk with row&7
__device__ __forceinline__ int SW(int row, int k) {
  return row * 64 + (k ^ ((row & 7) << 3));
}

// ---------- W pre-split into fragment-linear layout ------------------------
// wf[((which*16+kt)*16 + slot)*512 + lane*8 + j]:
//   slot s=ks*4+ct (0..7) hi-frag, s+8 lo-frag;
//   element = W[k][col]*scale, col=ct*16+(lane&15), k=kt*64+ks*32+(lane>>4)*8+j
__global__ __launch_bounds__(256) void wsplit_kernel(
    const float* __restrict__ Wq, const float* __restrict__ Wk,
    const float* __restrict__ Wv, _Float16* __restrict__ wf)
{
  const int which = blockIdx.x;   // 0..2
  const int kt    = blockIdx.y;   // 0..15
  const float* __restrict__ W = (which == 0) ? Wq : (which == 1) ? Wk : Wv;
  const float scale = (which == 0) ? 0.18033688011112042f : 1.0f;  // log2(e)/8
  const size_t tb = ((size_t)which * 16 + kt) * 8192;
#pragma unroll
  for (int i = 0; i < 2; ++i) {
    const int pair = threadIdx.x + 256 * i;   // 0..511
    const int lane = pair & 63, f = pair >> 6;  // f = ks*4+ct in 0..7
    const int ks = f >> 2, ct = f & 3;
    const int col = ct * 16 + (lane & 15);
    const int k0 = kt * 64 + ks * 32 + (lane >> 4) * 8;
    f16x8 hv, lv;
#pragma unroll
    for (int j = 0; j < 8; ++j) {
      const float y = W[(size_t)(k0 + j) * HD + col] * scale;
      const _Float16 h = (_Float16)y;
      hv[j] = h;
      lv[j] = (_Float16)(y - (float)h);
    }
    *(f16x8*)&wf[tb + (size_t)f * 512 + lane * 8]       = hv;
    *(f16x8*)&wf[tb + (size_t)(8 + f) * 512 + lane * 8] = lv;
  }
}

// ---------- projection: reg-staged fp16x3 MFMA, counted waits --------------
// grid (256, 3), 256 threads (4 waves x 16 rows). Y = X[16384,1024]@W[1024,64]
// Per K-step: vmcnt(0) [regs ready] -> 8 ds_write_b128 -> issue next tile's
// 8 global loads (fly across the barrier) -> lgkmcnt(0)+s_barrier ->
// 12 ds_read_b128 + 24 MFMA. LDS 64 KB -> 2 blocks/CU.
__global__ __launch_bounds__(256, 2) void proj_kernel(
    const float* __restrict__ Xq, const float* __restrict__ Xk,
    const float* __restrict__ Xv,
    const _Float16* __restrict__ wf,
    _Float16* __restrict__ qh, _Float16* __restrict__ ql,
    _Float16* __restrict__ kh, _Float16* __restrict__ kl,
    _Float16* __restrict__ vt)
{
  __shared__ __attribute__((aligned(16))) float    Xs[2][64 * 64];  // 16 KB ea
  __shared__ __attribute__((aligned(16))) _Float16 Ws[2][8192];     // 16 KB ea

  const int which = blockIdx.y;
  const float* __restrict__ X = (which == 0) ? Xq : (which == 1) ? Xk : Xv;

  const int t = threadIdx.x, lane = t & 63, w = t >> 6;
  const int bm = blockIdx.x * 64;

  // X: thread loads 4 chunks, rows w*16+i*4+(lane>>4), chunk col lane&15
  // (linear, coalesced); writes to swizzled slot (lane&15)^(row&15).
  // Each wave writes AND reads only its own rows w*16..w*16+15.
  const float* gX[4];
  int xdst[4];
#pragma unroll
  for (int i = 0; i < 4; ++i) {
    const int row = w * 16 + i * 4 + (lane >> 4);
    gX[i] = X + (size_t)(bm + row) * DIM + (lane & 15) * 4;
    xdst[i] = row * 64 + (((lane & 15) ^ (row & 15)) * 4);
  }
  // W: linear 16 KB tile, thread's 4 chunks at slab (w*4+i)*512 + lane*8
  const _Float16* gW[4];
  int wdst[4];
#pragma unroll
  for (int i = 0; i < 4; ++i) {
    gW[i] = wf + (size_t)which * 16 * 8192 + (w * 4 + i) * 512 + lane * 8;
    wdst[i] = (w * 4 + i) * 512 + lane * 8;
  }

  const int frow = lane & 15;
  const int ldsrow = w * 16 + frow;

  f32x4 acc[4] = {{0,0,0,0},{0,0,0,0},{0,0,0,0},{0,0,0,0}};
  f32x4 xr[4];
  f16x8 wr[4];

  auto loadTile = [&](int kt) {
#pragma unroll
    for (int i = 0; i < 4; ++i) xr[i] = *(const f32x4*)(gX[i] + kt * 64);
#pragma unroll
    for (int i = 0; i < 4; ++i) wr[i] = *(const f16x8*)(gW[i] + (size_t)kt * 8192);
  };

  // prologue: tile 0 loads in flight
  loadTile(0);

  for (int kt = 0; kt < DIM / 64; ++kt) {
    const int buf = kt & 1;
    // regs for tile kt ready (loads had the previous compute phase to fly)
    asm volatile("s_waitcnt vmcnt(0)" ::: "memory");
    __builtin_amdgcn_sched_barrier(0);
#pragma unroll
    for (int i = 0; i < 4; ++i) *(f32x4*)&Xs[buf][xdst[i]] = xr[i];
#pragma unroll
    for (int i = 0; i < 4; ++i) *(f16x8*)&Ws[buf][wdst[i]] = wr[i];
    if (kt + 1 < DIM / 64) loadTile(kt + 1);   // flies across the barrier
    asm volatile("s_waitcnt lgkmcnt(0)" ::: "memory");
    __builtin_amdgcn_sched_barrier(0);
    __builtin_amdgcn_s_barrier();              // all waves' writes visible
    __builtin_amdgcn_sched_barrier(0);

    // ---- compute tile kt from LDS
#pragma unroll
    for (int ks = 0; ks < 2; ++ks) {
      const int cc0 = ks * 8 + (lane >> 4) * 2;
      f32x4 x0 = *(const f32x4*)&Xs[buf][ldsrow * 64 + ((cc0 ^ frow) * 4)];
      f32x4 x1 = *(const f32x4*)&Xs[buf][ldsrow * 64 + (((cc0 + 1) ^ frow) * 4)];
      f16x8 xh, xl;
#pragma unroll
      for (int j = 0; j < 4; ++j) {
        const _Float16 h = (_Float16)x0[j];
        xh[j] = h; xl[j] = (_Float16)(x0[j] - (float)h);
      }
#pragma unroll
      for (int j = 0; j < 4; ++j) {
        const _Float16 h = (_Float16)x1[j];
        xh[j + 4] = h; xl[j + 4] = (_Float16)(x1[j] - (float)h);
      }
#pragma unroll
      for (int ct = 0; ct < 4; ++ct) {
        f16x8 bh = *(const f16x8*)&Ws[buf][(ks * 4 + ct) * 512 + lane * 8];
        f16x8 bl = *(const f16x8*)&Ws[buf][(8 + ks * 4 + ct) * 512 + lane * 8];
        acc[ct] = MFMA16(xh, bh, acc[ct], 0, 0, 0);
        acc[ct] = MFMA16(xl, bh, acc[ct], 0, 0, 0);
        acc[ct] = MFMA16(xh, bl, acc[ct], 0, 0, 0);
      }
    }
  }

  // epilogue: C layout col=lane&15, row=(lane>>4)*4+r
  const size_t orow0 = (size_t)bm + w * 16 + (lane >> 4) * 4;
  if (which < 2) {
    _Float16* oh = (which == 0) ? qh : kh;
    _Float16* ol = (which == 0) ? ql : kl;
#pragma unroll
    for (int ct = 0; ct < 4; ++ct)
#pragma unroll
      for (int r = 0; r < 4; ++r) {
        const float y = acc[ct][r];
        const _Float16 h = (_Float16)y;
        const size_t idx = (orow0 + r) * HD + ct * 16 + (lane & 15);
        oh[idx] = h;
        ol[idx] = (_Float16)(y - (float)h);
      }
  } else {
    const int batch = (int)(orow0 >> 12);
    const int pos = (int)(orow0 & 4095);
#pragma unroll
    for (int ct = 0; ct < 4; ++ct) {
      f16x4 hv;
#pragma unroll
      for (int r = 0; r < 4; ++r) hv[r] = (_Float16)acc[ct][r];
      *(f16x4*)&vt[((size_t)batch * HD + ct * 16 + (lane & 15)) * SEQ + pos] = hv;
    }
  }
}

// ---------- flash attention, fp16x3 QK + f16 PV, split-4 partials ----------
// grid (128, 4): x -> pair p=x>>2 (q-blocks p and 63-p), parity s=x&3.
__global__ __launch_bounds__(256) void attn_kernel(
    const _Float16* __restrict__ qh, const _Float16* __restrict__ ql,
    const _Float16* __restrict__ kh, const _Float16* __restrict__ kl,
    const _Float16* __restrict__ vt,
    _Float16* __restrict__ opart, float* __restrict__ mlp)
{
  __shared__ __attribute__((aligned(16))) _Float16 Ksh[64 * 64];
  __shared__ __attribute__((aligned(16))) _Float16 Ksl[64 * 64];
  __shared__ __attribute__((aligned(16))) _Float16 Vs [64 * 64];
  __shared__ __attribute__((aligned(16))) _Float16 Pt [64 * 64];

  const int t = threadIdx.x, lane = t & 63, w = t >> 6;
  const int b = blockIdx.y;
  const int p = blockIdx.x >> 2, s = blockIdx.x & 3;
  const size_t bS = (size_t)b * SEQ;

  for (int sel = 0; sel < 2; ++sel) {
    const int qb = sel ? (63 - p) : p;
    const int qrow0 = qb * 64 + w * 16;
    const int nt = (qb >= s) ? ((qb - s) >> 2) + 1 : 0;  // kv tiles ≡ s mod 4

    float m[4] = {-INFINITY, -INFINITY, -INFINITY, -INFINITY};
    float lsum[4] = {0.f, 0.f, 0.f, 0.f};
    f32x4 o[4] = {{0,0,0,0},{0,0,0,0},{0,0,0,0},{0,0,0,0}};

    if (nt > 0) {
      const _Float16* qhp = qh + (bS + qrow0 + (lane & 15)) * HD + ((lane >> 4) * 8);
      const _Float16* qlp = ql + (bS + qrow0 + (lane & 15)) * HD + ((lane >> 4) * 8);
      f16x8 qhf[2], qlf[2];
      qhf[0] = *(const f16x8*)(qhp);      qhf[1] = *(const f16x8*)(qhp + 32);
      qlf[0] = *(const f16x8*)(qlp);      qlf[1] = *(const f16x8*)(qlp + 32);

      for (int i = 0; i < nt; ++i) {
        const int kt = s + 4 * i;
        const int j0 = kt * 64;

        __syncthreads();  // previous tile's LDS reads complete
#pragma unroll
        for (int c = 0; c < 2; ++c) {
          const int lin = t + 256 * c;
          const int row = lin >> 3, d8 = (lin & 7) * 8;
          const int dst = SW(row, d8);
          *(f16x8*)&Ksh[dst] = *(const f16x8*)&kh[(bS + j0 + row) * HD + d8];
          *(f16x8*)&Ksl[dst] = *(const f16x8*)&kl[(bS + j0 + row) * HD + d8];
          *(f16x8*)&Vs[dst]  = *(const f16x8*)&vt[((size_t)b * HD + row) * SEQ + j0 + d8];
        }
        __syncthreads();

        // ---- QK^T: fp16x3
        f32x4 sacc[4] = {{0,0,0,0},{0,0,0,0},{0,0,0,0},{0,0,0,0}};
#pragma unroll
        for (int ks = 0; ks < 2; ++ks)
#pragma unroll
          for (int kt4 = 0; kt4 < 4; ++kt4) {
            const int ba = SW(kt4 * 16 + (lane & 15), ks * 32 + (lane >> 4) * 8);
            f16x8 bh = *(const f16x8*)&Ksh[ba];
            f16x8 bl = *(const f16x8*)&Ksl[ba];
            sacc[kt4] = MFMA16(qhf[ks], bh, sacc[kt4], 0, 0, 0);
            sacc[kt4] = MFMA16(qlf[ks], bh, sacc[kt4], 0, 0, 0);
            sacc[kt4] = MFMA16(qhf[ks], bl, sacc[kt4], 0, 0, 0);
          }

        // ---- causal mask on the diagonal tile
        if (kt == qb) {
#pragma unroll
          for (int kt4 = 0; kt4 < 4; ++kt4) {
            const int key = j0 + kt4 * 16 + (lane & 15);
#pragma unroll
            for (int r = 0; r < 4; ++r)
              if (key > qrow0 + (lane >> 4) * 4 + r) sacc[kt4][r] = -INFINITY;
          }
        }

        // ---- online softmax (exp2 domain), P -> LDS f16
        float alf[4];
#pragma unroll
        for (int r = 0; r < 4; ++r) {
          float mx = fmaxf(fmaxf(sacc[0][r], sacc[1][r]),
                           fmaxf(sacc[2][r], sacc[3][r]));
          mx = fmaxf(mx, __shfl_xor(mx, 1));
          mx = fmaxf(mx, __shfl_xor(mx, 2));
          mx = fmaxf(mx, __shfl_xor(mx, 4));
          mx = fmaxf(mx, __shfl_xor(mx, 8));
          const float mn = fmaxf(m[r], mx);
          const float al = exp2f(m[r] - mn);
          const int prow = w * 16 + (lane >> 4) * 4 + r;
          float ps = 0.f;
#pragma unroll
          for (int kt4 = 0; kt4 < 4; ++kt4) {
            const _Float16 ph = (_Float16)exp2f(sacc[kt4][r] - mn);
            ps += (float)ph;
            Pt[SW(prow, kt4 * 16 + (lane & 15))] = ph;
          }
          ps += __shfl_xor(ps, 1);
          ps += __shfl_xor(ps, 2);
          ps += __shfl_xor(ps, 4);
          ps += __shfl_xor(ps, 8);
          lsum[r] = lsum[r] * al + ps;
          m[r] = mn;
          alf[r] = al;
        }
        const f32x4 av = {alf[0], alf[1], alf[2], alf[3]};
#pragma unroll
        for (int ct = 0; ct < 4; ++ct) o[ct] *= av;

        // ---- PV (per-wave Pt region)
#pragma unroll
        for (int ks = 0; ks < 2; ++ks) {
          f16x8 pa = *(const f16x8*)&Pt[SW(w * 16 + (lane & 15),
                                           ks * 32 + (lane >> 4) * 8)];
#pragma unroll
          for (int ct = 0; ct < 4; ++ct) {
            f16x8 vb = *(const f16x8*)&Vs[SW(ct * 16 + (lane & 15),
                                             ks * 32 + (lane >> 4) * 8)];
            o[ct] = MFMA16(pa, vb, o[ct], 0, 0, 0);
          }
        }
      }
    }

    // ---- write partials: normalized o (f16) + (m, l) f32
    f32x4 invv;
#pragma unroll
    for (int r = 0; r < 4; ++r) invv[r] = (nt > 0) ? 1.0f / lsum[r] : 0.0f;
    const size_t ridx0 = (size_t)(b * NSPLIT + s) * SEQ + qrow0 + (lane >> 4) * 4;
#pragma unroll
    for (int ct = 0; ct < 4; ++ct)
#pragma unroll
      for (int r = 0; r < 4; ++r)
        opart[(ridx0 + r) * HD + ct * 16 + (lane & 15)] =
            (_Float16)(o[ct][r] * invv[r]);
    if ((lane & 15) == 0) {
#pragma unroll
      for (int r = 0; r < 4; ++r) {
        mlp[(ridx0 + r) * 2]     = m[r];
        mlp[(ridx0 + r) * 2 + 1] = lsum[r];
      }
    }
  }
}

// ---------- combine the 4 kv-parity partials -------------------------------
__global__ __launch_bounds__(256) void combine_kernel(
    const _Float16* __restrict__ opart, const float* __restrict__ mlp,
    float* __restrict__ out)
{
  const int g = blockIdx.x * 256 + threadIdx.x;   // 262144
  const int row = g >> 4;
  const int cq = (g & 15) * 4;
  const int b = row >> 12, pos = row & 4095;

  float mv[4], lv[4], msx = -INFINITY;
#pragma unroll
  for (int s = 0; s < 4; ++s) {
    const size_t ri = (size_t)(b * NSPLIT + s) * SEQ + pos;
    mv[s] = mlp[ri * 2];
    lv[s] = mlp[ri * 2 + 1];
    msx = fmaxf(msx, mv[s]);
  }
  f32x4 num = {0.f, 0.f, 0.f, 0.f};
  float L = 0.f;
#pragma unroll
  for (int s = 0; s < 4; ++s) {
    const float wgt = lv[s] * exp2f(mv[s] - msx);
    L += wgt;
    const size_t ri = (size_t)(b * NSPLIT + s) * SEQ + pos;
    const f16x4 ov = *(const f16x4*)&opart[ri * HD + cq];
#pragma unroll
    for (int j = 0; j < 4; ++j) num[j] += wgt * (float)ov[j];
  }
  const float inv = 1.0f / L;
  f32x4 res = {num[0] * inv, num[1] * inv, num[2] * inv, num[3] * inv};
  *(f32x4*)&out[(size_t)row * HD + cq] = res;
}

extern "C" void kernel_launch(void* const* d_in, const int* in_sizes, int n_in,
                              void* d_out, int out_size, void* d_ws, size_t ws_size,
                              hipStream_t stream) {
  const float* query = (const float*)d_in[0];
  const float* key   = (const float*)d_in[1];
  const float* value = (const float*)d_in[2];
  const float* Wq    = (const float*)d_in[3];
  const float* Wk    = (const float*)d_in[4];
  const float* Wv    = (const float*)d_in[5];
  // d_in[6]: causal mask, handled analytically.

  float* out = (float*)d_out;

  _Float16* qh  = (_Float16*)d_ws;
  _Float16* ql  = qh  + (size_t)NB * SEQ * HD;
  _Float16* kh  = ql  + (size_t)NB * SEQ * HD;
  _Float16* kl  = kh  + (size_t)NB * SEQ * HD;
  _Float16* vt  = kl  + (size_t)NB * SEQ * HD;           // [b][64][4096]
  _Float16* wf  = vt  + (size_t)NB * SEQ * HD;           // [3][16][16][512]
  _Float16* opart = wf + (size_t)3 * 16 * 8192;          // [b*4+s][4096][64]
  float* mlp = (float*)(opart + (size_t)NB * NSPLIT * SEQ * HD);

  wsplit_kernel<<<dim3(3, 16), 256, 0, stream>>>(Wq, Wk, Wv, wf);
  proj_kernel<<<dim3(256, 3), 256, 0, stream>>>(query, key, value, wf,
                                                qh, ql, kh, kl, vt);
  attn_kernel<<<dim3(128, NB), 256, 0, stream>>>(qh, ql, kh, kl, vt, opart, mlp);
  combine_kernel<<<1024, 256, 0, stream>>>(opart, mlp, out);
}